// Round 9
// baseline (451.821 us; speedup 1.0000x reference)
//
#include <hip/hip_runtime.h>

#define Nn 50000
#define Dd 64
#define Ee 800000
#define Ll 3
#define Rr 2
#define Gg 128
#define Cc 10
#define NR (Nn * Rr)
#define NB ((NR + 1023) / 1024)
#define NT (Nn / 16)   // 3125 tasks

// k_setup block ranges (all exact multiples of 256)
#define CVT_B  3125    // Nn*Dd/4 / 256
#define PREP_B 240     // 15*4096 / 256
#define HIST_B 3125    // Ee / 256

typedef __attribute__((ext_vector_type(8))) short short8;
typedef __attribute__((ext_vector_type(4))) float f32x4;

__device__ __forceinline__ unsigned short bf16_rne(float x) {
  unsigned u = __float_as_uint(x);
  unsigned r = u + 0x7fffu + ((u >> 16) & 1u);
  return (unsigned short)(r >> 16);
}
__device__ __forceinline__ float bf16_tof(unsigned short b) {
  return __uint_as_float(((unsigned)b) << 16);
}
// accumulate 8 bf16 (packed in uint4) into z[0..7], f32
__device__ __forceinline__ void acc8(float* z, uint4 u) {
  z[0] += __uint_as_float(u.x << 16);
  z[1] += __uint_as_float(u.x & 0xffff0000u);
  z[2] += __uint_as_float(u.y << 16);
  z[3] += __uint_as_float(u.y & 0xffff0000u);
  z[4] += __uint_as_float(u.z << 16);
  z[5] += __uint_as_float(u.z & 0xffff0000u);
  z[6] += __uint_as_float(u.w << 16);
  z[7] += __uint_as_float(u.w & 0xffff0000u);
}

// ========== fused setup: x->bf16 shadow | weight split-bf16 prep | hist =====
__global__ __launch_bounds__(256) void k_setup(
    const float* __restrict__ x, unsigned short* __restrict__ hb,
    const float* __restrict__ selfW, const float* __restrict__ W1,
    const float* __restrict__ W2, unsigned short* __restrict__ wtHi,
    unsigned short* __restrict__ wtLo,
    const int* __restrict__ dst, const int* __restrict__ et,
    int* __restrict__ counts)
{
  int b = blockIdx.x;
  if (b < CVT_B) {
    int i = b * 256 + threadIdx.x;            // < 800000 exactly
    const float4 v = *(const float4*)&x[(size_t)i * 4];
    ushort4 o;
    o.x = bf16_rne(v.x); o.y = bf16_rne(v.y);
    o.z = bf16_rne(v.z); o.w = bf16_rne(v.w);
    *(ushort4*)&hb[(size_t)i * 4] = o;
  } else if (b < CVT_B + PREP_B) {
    int i = (b - CVT_B) * 256 + threadIdx.x;  // < 61440 exactly
    int l = i / (5 * 4096);
    int rem = i - l * 5 * 4096;
    int m = rem >> 12;
    int e = rem & 4095;
    int k = e >> 6, c = e & 63;
    const float* p;
    if (m == 0)      p = selfW + (size_t)l * 4096;
    else if (m == 1) p = W1 + ((size_t)l * 2 + 0) * 4096;
    else if (m == 2) p = W2 + ((size_t)l * 2 + 0) * 4096;
    else if (m == 3) p = W1 + ((size_t)l * 2 + 1) * 4096;
    else             p = W2 + ((size_t)l * 2 + 1) * 4096;
    float w = p[e];
    unsigned short hi = bf16_rne(w);
    unsigned short lo = bf16_rne(w - bf16_tof(hi));
    size_t o = ((size_t)(l * 5 + m) * 64 + c) * 64 + k;
    wtHi[o] = hi;
    wtLo[o] = lo;
  } else {
    int e = (b - CVT_B - PREP_B) * 256 + threadIdx.x;  // < Ee exactly
    atomicAdd(&counts[et[e] * Nn + dst[e]], 1);
  }
}

// ====== degree-sorted permutation (counting sort, 128 bins) =================
__global__ __launch_bounds__(256) void k_deghist(
    const int* __restrict__ counts, int* __restrict__ binh)
{
  __shared__ int lh[128];
  if (threadIdx.x < 128) lh[threadIdx.x] = 0;
  __syncthreads();
  int n = blockIdx.x * 256 + threadIdx.x;
  if (n < Nn) {
    int t = min(counts[n] + counts[Nn + n], 127);
    atomicAdd(&lh[t], 1);
  }
  __syncthreads();
  if (threadIdx.x < 128 && lh[threadIdx.x] > 0)
    atomicAdd(&binh[threadIdx.x], lh[threadIdx.x]);
}

__global__ __launch_bounds__(128) void k_binscan(
    const int* __restrict__ binh, int* __restrict__ bincur)
{
  __shared__ int s[128];
  int v = binh[threadIdx.x];
  s[threadIdx.x] = v;
  __syncthreads();
#pragma unroll
  for (int d = 1; d < 128; d <<= 1) {
    int t = (threadIdx.x >= d) ? s[threadIdx.x - d] : 0;
    __syncthreads();
    s[threadIdx.x] += t;
    __syncthreads();
  }
  bincur[threadIdx.x] = s[threadIdx.x] - v;  // exclusive
}

__global__ __launch_bounds__(256) void k_scatterp(
    const int* __restrict__ counts, int* __restrict__ bincur,
    int* __restrict__ nodeof, int* __restrict__ permpos)
{
  int n = blockIdx.x * 256 + threadIdx.x;
  if (n >= Nn) return;
  int t = min(counts[n] + counts[Nn + n], 127);
  int p = atomicAdd(&bincur[t], 1);
  nodeof[p] = n;
  permpos[n] = p;
}

// ================= CSR scan + fill (over permuted node order) ===============
__global__ __launch_bounds__(1024) void k_scan1(
    const int* __restrict__ counts, const int* __restrict__ nodeof,
    int* __restrict__ offs, int* __restrict__ btot)
{
  __shared__ int s[1024];
  int i = blockIdx.x * 1024 + threadIdx.x;
  int v = 0;
  if (i < NR) {
    int rbase = (i >= Nn) ? Nn : 0;
    v = counts[rbase + nodeof[i - rbase]];
  }
  s[threadIdx.x] = v;
  __syncthreads();
#pragma unroll
  for (int d = 1; d < 1024; d <<= 1) {
    int t = (threadIdx.x >= d) ? s[threadIdx.x - d] : 0;
    __syncthreads();
    s[threadIdx.x] += t;
    __syncthreads();
  }
  if (i < NR) offs[i + 1] = s[threadIdx.x];
  if (threadIdx.x == 1023) btot[blockIdx.x] = s[1023];
}

__global__ __launch_bounds__(128) void k_scan2(
    const int* __restrict__ btot, int* __restrict__ bscan)
{
  __shared__ int s[128];
  int v = (threadIdx.x < NB) ? btot[threadIdx.x] : 0;
  s[threadIdx.x] = v;
  __syncthreads();
#pragma unroll
  for (int d = 1; d < 128; d <<= 1) {
    int t = (threadIdx.x >= d) ? s[threadIdx.x - d] : 0;
    __syncthreads();
    s[threadIdx.x] += t;
    __syncthreads();
  }
  if (threadIdx.x < NB) bscan[threadIdx.x] = s[threadIdx.x] - v;  // exclusive
}

__global__ __launch_bounds__(1024) void k_scan3(
    const int* __restrict__ counts, const int* __restrict__ nodeof,
    const int* __restrict__ bscan, int* __restrict__ offs,
    int* __restrict__ cursor)
{
  int i = blockIdx.x * 1024 + threadIdx.x;
  if (i >= NR) return;
  int o = offs[i + 1] + bscan[blockIdx.x];
  offs[i + 1] = o;
  int rbase = (i >= Nn) ? Nn : 0;
  cursor[i] = o - counts[rbase + nodeof[i - rbase]];
  if (i == 0) offs[0] = 0;
}

__global__ __launch_bounds__(256) void k_fill(
    const int* __restrict__ src, const int* __restrict__ dst,
    const int* __restrict__ et, const int* __restrict__ permpos,
    int* __restrict__ cursor, int* __restrict__ elist)
{
  int e = blockIdx.x * 256 + threadIdx.x;
  if (e >= Ee) return;
  int pos = atomicAdd(&cursor[et[e] * Nn + permpos[dst[e]]], 1);
  elist[pos] = src[e];
}

// ====== fused per-layer update: (task, relation) per wave + LDS combine =====
#define WOFF(m, c, ks) ((size_t)(m)*4096 + (size_t)(c)*64 + (ks)*32 + koff)

__global__ __launch_bounds__(128, 5) void k_update(
    const float* __restrict__ h, const unsigned short* __restrict__ hb,
    const int* __restrict__ offs, const int* __restrict__ elist,
    const int* __restrict__ nodeof,
    const unsigned short* __restrict__ wtHi, const unsigned short* __restrict__ wtLo,
    const float* __restrict__ selfb, const float* __restrict__ eps,
    const float* __restrict__ b1, const float* __restrict__ b2,
    float* __restrict__ hn, unsigned short* __restrict__ hnb, int l)
{
  __shared__ __align__(16) unsigned short tbh[2][16 * 72];  // 4608 B
  __shared__ __align__(16) unsigned short tbl[2][16 * 72];  // 4608 B
  float* xfer = (float*)&tbh[0][0];     // aliased: tb dead by combine time
  const int wave = threadIdx.x >> 6;    // = relation r
  const int lane = threadIdx.x & 63;
  const int task = blockIdx.x;
  const int r = wave;
  const int idx15 = lane & 15;
  const int kg = lane >> 4;
  const int koff = kg * 8;
  const int ppos = task * 16 + idx15;   // permuted position
  const int nodeA = nodeof[ppos];       // actual node

  // h row fragment (row = idx15, features koff..koff+7 per kstep), f32
  float f[2][8];
  {
    const float* hp = &h[(size_t)nodeA * 64 + koff];
    const float4 a0 = *(const float4*)(hp);
    const float4 a1 = *(const float4*)(hp + 4);
    const float4 b0 = *(const float4*)(hp + 32);
    const float4 b1v = *(const float4*)(hp + 36);
    f[0][0] = a0.x; f[0][1] = a0.y; f[0][2] = a0.z; f[0][3] = a0.w;
    f[0][4] = a1.x; f[0][5] = a1.y; f[0][6] = a1.z; f[0][7] = a1.w;
    f[1][0] = b0.x; f[1][1] = b0.y; f[1][2] = b0.z; f[1][3] = b0.w;
    f[1][4] = b1v.x; f[1][5] = b1v.y; f[1][6] = b1v.z; f[1][7] = b1v.w;
  }

  const unsigned short* whi = wtHi + (size_t)l * 5 * 4096;
  const unsigned short* wlo = wtLo + (size_t)l * 5 * 4096;
  const int m1 = 1 + 2 * r, m2 = 2 + 2 * r;
  const float er = 1.0f + eps[l * Rr + r];

  // ---- CSR gather for relation r, bf16 rows (128 B/edge), 4-deep pipelined -
  float za[2][8];
#pragma unroll
  for (int ks = 0; ks < 2; ++ks)
#pragma unroll
    for (int j = 0; j < 8; ++j) za[ks][j] = 0.0f;
  {
    int aidx = r * Nn + ppos;
    int jb = offs[aidx], je = offs[aidx + 1];
    int j = jb;
    for (; j + 3 < je; j += 4) {
      int s0 = elist[j], s1 = elist[j + 1], s2 = elist[j + 2], s3 = elist[j + 3];
      const unsigned short* q0 = &hb[(size_t)s0 * 64 + koff];
      const unsigned short* q1 = &hb[(size_t)s1 * 64 + koff];
      const unsigned short* q2 = &hb[(size_t)s2 * 64 + koff];
      const unsigned short* q3 = &hb[(size_t)s3 * 64 + koff];
      const uint4 a0 = *(const uint4*)(q0);
      const uint4 a1 = *(const uint4*)(q1);
      const uint4 a2 = *(const uint4*)(q2);
      const uint4 a3 = *(const uint4*)(q3);
      const uint4 b0 = *(const uint4*)(q0 + 32);
      const uint4 b1q = *(const uint4*)(q1 + 32);
      const uint4 b2q = *(const uint4*)(q2 + 32);
      const uint4 b3 = *(const uint4*)(q3 + 32);
      acc8(za[0], a0); acc8(za[0], a1); acc8(za[0], a2); acc8(za[0], a3);
      acc8(za[1], b0); acc8(za[1], b1q); acc8(za[1], b2q); acc8(za[1], b3);
    }
    for (; j < je; ++j) {
      const unsigned short* q = &hb[(size_t)elist[j] * 64 + koff];
      const uint4 a = *(const uint4*)(q);
      const uint4 b = *(const uint4*)(q + 32);
      acc8(za[0], a); acc8(za[1], b);
    }
  }

  // z = er*h + za -> split bf16
  short8 zhi[2], zlo[2];
#pragma unroll
  for (int ks = 0; ks < 2; ++ks)
#pragma unroll
    for (int j = 0; j < 8; ++j) {
      float zf = er * f[ks][j] + za[ks][j];
      unsigned short hb2 = bf16_rne(zf);
      zhi[ks][j] = (short)hb2;
      zlo[ks][j] = (short)bf16_rne(zf - bf16_tof(hb2));
    }

  // MLP1: tacc = relu(z @ W1_r + b1_r)
  f32x4 tacc[4];
#pragma unroll
  for (int cb = 0; cb < 4; ++cb) {
    float bi = b1[((size_t)l * 2 + r) * 64 + cb * 16 + idx15];
    tacc[cb] = (f32x4){bi, bi, bi, bi};
  }
#pragma unroll
  for (int cb = 0; cb < 4; ++cb) {
    int c = cb * 16 + idx15;
#pragma unroll
    for (int ks = 0; ks < 2; ++ks) {
      const short8 bh = *(const short8*)&whi[WOFF(m1, c, ks)];
      const short8 bl = *(const short8*)&wlo[WOFF(m1, c, ks)];
      tacc[cb] = __builtin_amdgcn_mfma_f32_16x16x32_bf16(zhi[ks], bh, tacc[cb], 0, 0, 0);
      tacc[cb] = __builtin_amdgcn_mfma_f32_16x16x32_bf16(zhi[ks], bl, tacc[cb], 0, 0, 0);
      tacc[cb] = __builtin_amdgcn_mfma_f32_16x16x32_bf16(zlo[ks], bh, tacc[cb], 0, 0, 0);
    }
  }
  // relu -> split-bf16 -> LDS transpose bounce (per-wave buffer, no barrier)
#pragma unroll
  for (int cb = 0; cb < 4; ++cb)
#pragma unroll
    for (int q = 0; q < 4; ++q) {
      float tv = fmaxf(tacc[cb][q], 0.0f);
      unsigned short hb2 = bf16_rne(tv);
      tbh[wave][(kg * 4 + q) * 72 + cb * 16 + idx15] = hb2;
      tbl[wave][(kg * 4 + q) * 72 + cb * 16 + idx15] = bf16_rne(tv - bf16_tof(hb2));
    }
  asm volatile("s_waitcnt lgkmcnt(0)" ::: "memory");
  __builtin_amdgcn_sched_barrier(0);
  short8 thi[2], tlo[2];
#pragma unroll
  for (int ks = 0; ks < 2; ++ks) {
    thi[ks] = *(const short8*)&tbh[wave][idx15 * 72 + ks * 32 + koff];
    tlo[ks] = *(const short8*)&tbl[wave][idx15 * 72 + ks * 32 + koff];
  }

  // MLP2 (+ wave1: self GEMM); facc = partial output
  f32x4 facc[4];
#pragma unroll
  for (int cb = 0; cb < 4; ++cb) {
    int c = cb * 16 + idx15;
    float bi = b2[((size_t)l * 2 + r) * 64 + c];
    if (wave == 1) bi += selfb[l * 64 + c];
    facc[cb] = (f32x4){bi, bi, bi, bi};
  }
#pragma unroll
  for (int cb = 0; cb < 4; ++cb) {
    int c = cb * 16 + idx15;
#pragma unroll
    for (int ks = 0; ks < 2; ++ks) {
      const short8 bh = *(const short8*)&whi[WOFF(m2, c, ks)];
      const short8 bl = *(const short8*)&wlo[WOFF(m2, c, ks)];
      facc[cb] = __builtin_amdgcn_mfma_f32_16x16x32_bf16(thi[ks], bh, facc[cb], 0, 0, 0);
      facc[cb] = __builtin_amdgcn_mfma_f32_16x16x32_bf16(thi[ks], bl, facc[cb], 0, 0, 0);
      facc[cb] = __builtin_amdgcn_mfma_f32_16x16x32_bf16(tlo[ks], bh, facc[cb], 0, 0, 0);
    }
  }
  if (wave == 1) {
    short8 ahi[2], alo[2];
#pragma unroll
    for (int ks = 0; ks < 2; ++ks)
#pragma unroll
      for (int j = 0; j < 8; ++j) {
        unsigned short hb2 = bf16_rne(f[ks][j]);
        ahi[ks][j] = (short)hb2;
        alo[ks][j] = (short)bf16_rne(f[ks][j] - bf16_tof(hb2));
      }
#pragma unroll
    for (int cb = 0; cb < 4; ++cb) {
      int c = cb * 16 + idx15;
#pragma unroll
      for (int ks = 0; ks < 2; ++ks) {
        const short8 bh = *(const short8*)&whi[WOFF(0, c, ks)];
        const short8 bl = *(const short8*)&wlo[WOFF(0, c, ks)];
        facc[cb] = __builtin_amdgcn_mfma_f32_16x16x32_bf16(ahi[ks], bh, facc[cb], 0, 0, 0);
        facc[cb] = __builtin_amdgcn_mfma_f32_16x16x32_bf16(ahi[ks], bl, facc[cb], 0, 0, 0);
        facc[cb] = __builtin_amdgcn_mfma_f32_16x16x32_bf16(alo[ks], bh, facc[cb], 0, 0, 0);
      }
    }
  }
  __syncthreads();                      // all tb reads done -> safe to alias
  if (wave == 1) {
#pragma unroll
    for (int cb = 0; cb < 4; ++cb)
#pragma unroll
      for (int q = 0; q < 4; ++q)
        xfer[(kg * 4 + q) * 65 + cb * 16 + idx15] = facc[cb][q];
  }
  __syncthreads();
  if (wave == 0) {
    int nrow[4];
#pragma unroll
    for (int q = 0; q < 4; ++q) nrow[q] = nodeof[task * 16 + kg * 4 + q];
#pragma unroll
    for (int cb = 0; cb < 4; ++cb)
#pragma unroll
      for (int q = 0; q < 4; ++q) {
        int row = kg * 4 + q, col = cb * 16 + idx15;
        float v = facc[cb][q] + xfer[row * 65 + col];
        size_t o = (size_t)nrow[q] * 64 + col;
        hn[o] = v;
        hnb[o] = bf16_rne(v);
      }
  }
}

// ====== fused pool+head: wave per graph, binary-search segment, no atomics ==
__global__ __launch_bounds__(64) void k_poolhead(
    const float* __restrict__ h, const int* __restrict__ batch,
    const float* __restrict__ l1W, const float* __restrict__ l1b,
    const float* __restrict__ l2W, const float* __restrict__ l2b,
    float* __restrict__ out)
{
  int g = blockIdx.x;
  int lane = threadIdx.x;
  // [start, end) = rows of graph g (batch sorted ascending)
  int lo = 0, hi = Nn;
  while (lo < hi) { int mid = (lo + hi) >> 1; if (batch[mid] < g) lo = mid + 1; else hi = mid; }
  int start = lo;
  hi = Nn;
  while (lo < hi) { int mid = (lo + hi) >> 1; if (batch[mid] < g + 1) lo = mid + 1; else hi = mid; }
  int end = lo;

  float acc = 0.0f;
  int i = start;
  for (; i + 3 < end; i += 4) {
    float v0 = h[(size_t)i * 64 + lane];
    float v1 = h[(size_t)(i + 1) * 64 + lane];
    float v2 = h[(size_t)(i + 2) * 64 + lane];
    float v3 = h[(size_t)(i + 3) * 64 + lane];
    acc += (v0 + v1) + (v2 + v3);
  }
  for (; i < end; ++i) acc += h[(size_t)i * 64 + lane];
  float p = acc / fmaxf((float)(end - start), 1.0f);

  float t = l1b[lane];
#pragma unroll
  for (int k = 0; k < Dd; ++k)
    t += __shfl(p, k, 64) * l1W[k * Dd + lane];
  t = fmaxf(t, 0.0f);
  float o = (lane < Cc) ? l2b[lane] : 0.0f;
#pragma unroll
  for (int k = 0; k < Dd; ++k) {
    float w = (lane < Cc) ? l2W[k * Cc + lane] : 0.0f;
    o += __shfl(t, k, 64) * w;
  }
  if (lane < Cc) out[(size_t)g * Cc + lane] = o;
}

extern "C" void kernel_launch(void* const* d_in, const int* in_sizes, int n_in,
                              void* d_out, int out_size, void* d_ws, size_t ws_size,
                              hipStream_t stream)
{
  const float* x     = (const float*)d_in[0];
  const int*   ei    = (const int*)d_in[1];
  const int*   et    = (const int*)d_in[2];
  const int*   batch = (const int*)d_in[3];
  const float* selfW = (const float*)d_in[4];
  const float* selfb = (const float*)d_in[5];
  const float* eps   = (const float*)d_in[6];
  const float* W1    = (const float*)d_in[7];
  const float* b1    = (const float*)d_in[8];
  const float* W2    = (const float*)d_in[9];
  const float* b2    = (const float*)d_in[10];
  const float* l1W   = (const float*)d_in[11];
  const float* l1b   = (const float*)d_in[12];
  const float* l2W   = (const float*)d_in[13];
  const float* l2b   = (const float*)d_in[14];
  float* out = (float*)d_out;

  // ws layout:
  // buf0[N*D]f buf1[N*D]f hb0[N*D]u16 hb1[N*D]u16 wtHi/wtLo[15*4096]u16
  // counts[NR] binh[128] bincur[128] offs[NR+1] cursor[NR] btot[NB] bscan[NB]
  // elist[E] nodeof[Nn] permpos[Nn]
  float* buf0 = (float*)d_ws;
  float* buf1 = buf0 + (size_t)Nn * Dd;
  unsigned short* hb0 = (unsigned short*)(buf1 + (size_t)Nn * Dd);
  unsigned short* hb1 = hb0 + (size_t)Nn * Dd;
  unsigned short* wtHi = hb1 + (size_t)Nn * Dd;
  unsigned short* wtLo = wtHi + (size_t)Ll * 5 * 4096;
  int* counts  = (int*)(wtLo + (size_t)Ll * 5 * 4096);
  int* binh    = counts + NR;
  int* bincur  = binh + 128;
  int* offs    = bincur + 128;
  int* cursor  = offs + NR + 1;
  int* btot    = cursor + NR;
  int* bscan   = btot + NB;
  int* elist   = bscan + NB;
  int* nodeof  = elist + Ee;
  int* permpos = nodeof + Nn;

  const int* src = ei;
  const int* dst = ei + Ee;

  hipMemsetAsync(counts, 0, (size_t)(NR + 256) * sizeof(int), stream);
  k_setup<<<CVT_B + PREP_B + HIST_B, 256, 0, stream>>>(
      x, hb0, selfW, W1, W2, wtHi, wtLo, dst, et, counts);

  // degree-sorted permutation + CSR build over permuted order
  k_deghist<<<(Nn + 255) / 256, 256, 0, stream>>>(counts, binh);
  k_binscan<<<1, 128, 0, stream>>>(binh, bincur);
  k_scatterp<<<(Nn + 255) / 256, 256, 0, stream>>>(counts, bincur, nodeof, permpos);
  k_scan1<<<NB, 1024, 0, stream>>>(counts, nodeof, offs, btot);
  k_scan2<<<1, 128, 0, stream>>>(btot, bscan);
  k_scan3<<<NB, 1024, 0, stream>>>(counts, nodeof, bscan, offs, cursor);
  k_fill<<<(Ee + 255) / 256, 256, 0, stream>>>(src, dst, et, permpos, cursor, elist);

  const float* h = x;
  const unsigned short* hbc = hb0;
  float* hn = buf0;
  unsigned short* hnb = hb1;
  for (int l = 0; l < Ll; ++l) {
    k_update<<<NT, 128, 0, stream>>>(h, hbc, offs, elist, nodeof, wtHi, wtLo,
                                     selfb, eps, b1, b2, hn, hnb, l);
    h = hn;
    hbc = hnb;
    hn = (hn == buf0) ? buf1 : buf0;
    hnb = (hnb == hb0) ? hb1 : hb0;
  }
  k_poolhead<<<Gg, 64, 0, stream>>>(h, batch, l1W, l1b, l2W, l2b, out);
}

// Round 10
// 322.526 us; speedup vs baseline: 1.4009x; 1.4009x over previous
//
#include <hip/hip_runtime.h>

#define Nn 50000
#define Dd 64
#define Ee 800000
#define Ll 3
#define Rr 2
#define Gg 128
#define Cc 10
#define NR (Nn * Rr)
#define NB ((NR + 1023) / 1024)
#define NT (Nn / 16)   // 3125 tasks

// k_setup block ranges (all exact multiples of 256)
#define CVT_B  3125    // Nn*Dd/4 / 256
#define PREP_B 240     // 15*4096 / 256
#define HIST_B 3125    // Ee / 256

typedef __attribute__((ext_vector_type(8))) short short8;
typedef __attribute__((ext_vector_type(4))) float f32x4;

__device__ __forceinline__ unsigned short bf16_rne(float x) {
  unsigned u = __float_as_uint(x);
  unsigned r = u + 0x7fffu + ((u >> 16) & 1u);
  return (unsigned short)(r >> 16);
}
__device__ __forceinline__ float bf16_tof(unsigned short b) {
  return __uint_as_float(((unsigned)b) << 16);
}
// accumulate 8 bf16 (packed in uint4) into z[0..7], f32
__device__ __forceinline__ void acc8(float* z, uint4 u) {
  z[0] += __uint_as_float(u.x << 16);
  z[1] += __uint_as_float(u.x & 0xffff0000u);
  z[2] += __uint_as_float(u.y << 16);
  z[3] += __uint_as_float(u.y & 0xffff0000u);
  z[4] += __uint_as_float(u.z << 16);
  z[5] += __uint_as_float(u.z & 0xffff0000u);
  z[6] += __uint_as_float(u.w << 16);
  z[7] += __uint_as_float(u.w & 0xffff0000u);
}

// ========== fused setup: x->bf16 shadow | weight split-bf16 prep | hist =====
__global__ __launch_bounds__(256) void k_setup(
    const float* __restrict__ x, unsigned short* __restrict__ hb,
    const float* __restrict__ selfW, const float* __restrict__ W1,
    const float* __restrict__ W2, unsigned short* __restrict__ wtHi,
    unsigned short* __restrict__ wtLo,
    const int* __restrict__ dst, const int* __restrict__ et,
    int* __restrict__ counts)
{
  int b = blockIdx.x;
  if (b < CVT_B) {
    int i = b * 256 + threadIdx.x;            // < 800000 exactly
    const float4 v = *(const float4*)&x[(size_t)i * 4];
    ushort4 o;
    o.x = bf16_rne(v.x); o.y = bf16_rne(v.y);
    o.z = bf16_rne(v.z); o.w = bf16_rne(v.w);
    *(ushort4*)&hb[(size_t)i * 4] = o;
  } else if (b < CVT_B + PREP_B) {
    int i = (b - CVT_B) * 256 + threadIdx.x;  // < 61440 exactly
    int l = i / (5 * 4096);
    int rem = i - l * 5 * 4096;
    int m = rem >> 12;
    int e = rem & 4095;
    int k = e >> 6, c = e & 63;
    const float* p;
    if (m == 0)      p = selfW + (size_t)l * 4096;
    else if (m == 1) p = W1 + ((size_t)l * 2 + 0) * 4096;
    else if (m == 2) p = W2 + ((size_t)l * 2 + 0) * 4096;
    else if (m == 3) p = W1 + ((size_t)l * 2 + 1) * 4096;
    else             p = W2 + ((size_t)l * 2 + 1) * 4096;
    float w = p[e];
    unsigned short hi = bf16_rne(w);
    unsigned short lo = bf16_rne(w - bf16_tof(hi));
    size_t o = ((size_t)(l * 5 + m) * 64 + c) * 64 + k;
    wtHi[o] = hi;
    wtLo[o] = lo;
  } else {
    int e = (b - CVT_B - PREP_B) * 256 + threadIdx.x;  // < Ee exactly
    atomicAdd(&counts[et[e] * Nn + dst[e]], 1);
  }
}

// ====== degree-sorted permutation (counting sort, 128 bins) =================
__global__ __launch_bounds__(256) void k_deghist(
    const int* __restrict__ counts, int* __restrict__ binh)
{
  __shared__ int lh[128];
  if (threadIdx.x < 128) lh[threadIdx.x] = 0;
  __syncthreads();
  int n = blockIdx.x * 256 + threadIdx.x;
  if (n < Nn) {
    int t = min(counts[n] + counts[Nn + n], 127);
    atomicAdd(&lh[t], 1);
  }
  __syncthreads();
  if (threadIdx.x < 128 && lh[threadIdx.x] > 0)
    atomicAdd(&binh[threadIdx.x], lh[threadIdx.x]);
}

__global__ __launch_bounds__(128) void k_binscan(
    const int* __restrict__ binh, int* __restrict__ bincur)
{
  __shared__ int s[128];
  int v = binh[threadIdx.x];
  s[threadIdx.x] = v;
  __syncthreads();
#pragma unroll
  for (int d = 1; d < 128; d <<= 1) {
    int t = (threadIdx.x >= d) ? s[threadIdx.x - d] : 0;
    __syncthreads();
    s[threadIdx.x] += t;
    __syncthreads();
  }
  bincur[threadIdx.x] = s[threadIdx.x] - v;  // exclusive
}

// hierarchical: LDS rank within block, ONE global atomic per (block,bin)
__global__ __launch_bounds__(256) void k_scatterp(
    const int* __restrict__ counts, int* __restrict__ bincur,
    int* __restrict__ nodeof, int* __restrict__ permpos)
{
  __shared__ int lh[128];    // local per-bin count
  __shared__ int lbase[128]; // global base for this block's chunk per bin
  if (threadIdx.x < 128) lh[threadIdx.x] = 0;
  __syncthreads();
  int n = blockIdx.x * 256 + threadIdx.x;
  int t = 0, myrank = 0;
  if (n < Nn) {
    t = min(counts[n] + counts[Nn + n], 127);
    myrank = atomicAdd(&lh[t], 1);     // LDS atomic, low contention
  }
  __syncthreads();
  if (threadIdx.x < 128 && lh[threadIdx.x] > 0)
    lbase[threadIdx.x] = atomicAdd(&bincur[threadIdx.x], lh[threadIdx.x]);
  __syncthreads();
  if (n < Nn) {
    int p = lbase[t] + myrank;
    nodeof[p] = n;
    permpos[n] = p;
  }
}

// ================= CSR scan + fill (over permuted node order) ===============
__global__ __launch_bounds__(1024) void k_scan1(
    const int* __restrict__ counts, const int* __restrict__ nodeof,
    int* __restrict__ offs, int* __restrict__ btot)
{
  __shared__ int s[1024];
  int i = blockIdx.x * 1024 + threadIdx.x;
  int v = 0;
  if (i < NR) {
    int rbase = (i >= Nn) ? Nn : 0;
    v = counts[rbase + nodeof[i - rbase]];
  }
  s[threadIdx.x] = v;
  __syncthreads();
#pragma unroll
  for (int d = 1; d < 1024; d <<= 1) {
    int t = (threadIdx.x >= d) ? s[threadIdx.x - d] : 0;
    __syncthreads();
    s[threadIdx.x] += t;
    __syncthreads();
  }
  if (i < NR) offs[i + 1] = s[threadIdx.x];
  if (threadIdx.x == 1023) btot[blockIdx.x] = s[1023];
}

__global__ __launch_bounds__(128) void k_scan2(
    const int* __restrict__ btot, int* __restrict__ bscan)
{
  __shared__ int s[128];
  int v = (threadIdx.x < NB) ? btot[threadIdx.x] : 0;
  s[threadIdx.x] = v;
  __syncthreads();
#pragma unroll
  for (int d = 1; d < 128; d <<= 1) {
    int t = (threadIdx.x >= d) ? s[threadIdx.x - d] : 0;
    __syncthreads();
    s[threadIdx.x] += t;
    __syncthreads();
  }
  if (threadIdx.x < NB) bscan[threadIdx.x] = s[threadIdx.x] - v;  // exclusive
}

__global__ __launch_bounds__(1024) void k_scan3(
    const int* __restrict__ counts, const int* __restrict__ nodeof,
    const int* __restrict__ bscan, int* __restrict__ offs,
    int* __restrict__ cursor)
{
  int i = blockIdx.x * 1024 + threadIdx.x;
  if (i >= NR) return;
  int o = offs[i + 1] + bscan[blockIdx.x];
  offs[i + 1] = o;
  int rbase = (i >= Nn) ? Nn : 0;
  cursor[i] = o - counts[rbase + nodeof[i - rbase]];
  if (i == 0) offs[0] = 0;
}

__global__ __launch_bounds__(256) void k_fill(
    const int* __restrict__ src, const int* __restrict__ dst,
    const int* __restrict__ et, const int* __restrict__ permpos,
    int* __restrict__ cursor, int* __restrict__ elist)
{
  int e = blockIdx.x * 256 + threadIdx.x;
  if (e >= Ee) return;
  int pos = atomicAdd(&cursor[et[e] * Nn + permpos[dst[e]]], 1);
  elist[pos] = src[e];
}

// ====== fused per-layer update: (task, relation) per wave + LDS combine =====
#define WOFF(m, c, ks) ((size_t)(m)*4096 + (size_t)(c)*64 + (ks)*32 + koff)

__global__ __launch_bounds__(128, 5) void k_update(
    const float* __restrict__ h, const unsigned short* __restrict__ hb,
    const int* __restrict__ offs, const int* __restrict__ elist,
    const int* __restrict__ nodeof,
    const unsigned short* __restrict__ wtHi, const unsigned short* __restrict__ wtLo,
    const float* __restrict__ selfb, const float* __restrict__ eps,
    const float* __restrict__ b1, const float* __restrict__ b2,
    float* __restrict__ hn, unsigned short* __restrict__ hnb, int l)
{
  __shared__ __align__(16) unsigned short tbh[2][16 * 72];  // 4608 B
  __shared__ __align__(16) unsigned short tbl[2][16 * 72];  // 4608 B
  float* xfer = (float*)&tbh[0][0];     // aliased: tb dead by combine time
  const int wave = threadIdx.x >> 6;    // = relation r
  const int lane = threadIdx.x & 63;
  const int task = blockIdx.x;
  const int r = wave;
  const int idx15 = lane & 15;
  const int kg = lane >> 4;
  const int koff = kg * 8;
  const int ppos = task * 16 + idx15;   // permuted position
  const int nodeA = nodeof[ppos];       // actual node

  // h row fragment (row = idx15, features koff..koff+7 per kstep), f32
  float f[2][8];
  {
    const float* hp = &h[(size_t)nodeA * 64 + koff];
    const float4 a0 = *(const float4*)(hp);
    const float4 a1 = *(const float4*)(hp + 4);
    const float4 b0 = *(const float4*)(hp + 32);
    const float4 b1v = *(const float4*)(hp + 36);
    f[0][0] = a0.x; f[0][1] = a0.y; f[0][2] = a0.z; f[0][3] = a0.w;
    f[0][4] = a1.x; f[0][5] = a1.y; f[0][6] = a1.z; f[0][7] = a1.w;
    f[1][0] = b0.x; f[1][1] = b0.y; f[1][2] = b0.z; f[1][3] = b0.w;
    f[1][4] = b1v.x; f[1][5] = b1v.y; f[1][6] = b1v.z; f[1][7] = b1v.w;
  }

  const unsigned short* whi = wtHi + (size_t)l * 5 * 4096;
  const unsigned short* wlo = wtLo + (size_t)l * 5 * 4096;
  const int m1 = 1 + 2 * r, m2 = 2 + 2 * r;
  const float er = 1.0f + eps[l * Rr + r];

  // ---- CSR gather for relation r, bf16 rows (128 B/edge), 4-deep pipelined -
  float za[2][8];
#pragma unroll
  for (int ks = 0; ks < 2; ++ks)
#pragma unroll
    for (int j = 0; j < 8; ++j) za[ks][j] = 0.0f;
  {
    int aidx = r * Nn + ppos;
    int jb = offs[aidx], je = offs[aidx + 1];
    int j = jb;
    for (; j + 3 < je; j += 4) {
      int s0 = elist[j], s1 = elist[j + 1], s2 = elist[j + 2], s3 = elist[j + 3];
      const unsigned short* q0 = &hb[(size_t)s0 * 64 + koff];
      const unsigned short* q1 = &hb[(size_t)s1 * 64 + koff];
      const unsigned short* q2 = &hb[(size_t)s2 * 64 + koff];
      const unsigned short* q3 = &hb[(size_t)s3 * 64 + koff];
      const uint4 a0 = *(const uint4*)(q0);
      const uint4 a1 = *(const uint4*)(q1);
      const uint4 a2 = *(const uint4*)(q2);
      const uint4 a3 = *(const uint4*)(q3);
      const uint4 b0 = *(const uint4*)(q0 + 32);
      const uint4 b1q = *(const uint4*)(q1 + 32);
      const uint4 b2q = *(const uint4*)(q2 + 32);
      const uint4 b3 = *(const uint4*)(q3 + 32);
      acc8(za[0], a0); acc8(za[0], a1); acc8(za[0], a2); acc8(za[0], a3);
      acc8(za[1], b0); acc8(za[1], b1q); acc8(za[1], b2q); acc8(za[1], b3);
    }
    for (; j < je; ++j) {
      const unsigned short* q = &hb[(size_t)elist[j] * 64 + koff];
      const uint4 a = *(const uint4*)(q);
      const uint4 b = *(const uint4*)(q + 32);
      acc8(za[0], a); acc8(za[1], b);
    }
  }

  // z = er*h + za -> split bf16
  short8 zhi[2], zlo[2];
#pragma unroll
  for (int ks = 0; ks < 2; ++ks)
#pragma unroll
    for (int j = 0; j < 8; ++j) {
      float zf = er * f[ks][j] + za[ks][j];
      unsigned short hb2 = bf16_rne(zf);
      zhi[ks][j] = (short)hb2;
      zlo[ks][j] = (short)bf16_rne(zf - bf16_tof(hb2));
    }

  // MLP1: tacc = relu(z @ W1_r + b1_r)
  f32x4 tacc[4];
#pragma unroll
  for (int cb = 0; cb < 4; ++cb) {
    float bi = b1[((size_t)l * 2 + r) * 64 + cb * 16 + idx15];
    tacc[cb] = (f32x4){bi, bi, bi, bi};
  }
#pragma unroll
  for (int cb = 0; cb < 4; ++cb) {
    int c = cb * 16 + idx15;
#pragma unroll
    for (int ks = 0; ks < 2; ++ks) {
      const short8 bh = *(const short8*)&whi[WOFF(m1, c, ks)];
      const short8 bl = *(const short8*)&wlo[WOFF(m1, c, ks)];
      tacc[cb] = __builtin_amdgcn_mfma_f32_16x16x32_bf16(zhi[ks], bh, tacc[cb], 0, 0, 0);
      tacc[cb] = __builtin_amdgcn_mfma_f32_16x16x32_bf16(zhi[ks], bl, tacc[cb], 0, 0, 0);
      tacc[cb] = __builtin_amdgcn_mfma_f32_16x16x32_bf16(zlo[ks], bh, tacc[cb], 0, 0, 0);
    }
  }
  // relu -> split-bf16 -> LDS transpose bounce (per-wave buffer, no barrier)
#pragma unroll
  for (int cb = 0; cb < 4; ++cb)
#pragma unroll
    for (int q = 0; q < 4; ++q) {
      float tv = fmaxf(tacc[cb][q], 0.0f);
      unsigned short hb2 = bf16_rne(tv);
      tbh[wave][(kg * 4 + q) * 72 + cb * 16 + idx15] = hb2;
      tbl[wave][(kg * 4 + q) * 72 + cb * 16 + idx15] = bf16_rne(tv - bf16_tof(hb2));
    }
  asm volatile("s_waitcnt lgkmcnt(0)" ::: "memory");
  __builtin_amdgcn_sched_barrier(0);
  short8 thi[2], tlo[2];
#pragma unroll
  for (int ks = 0; ks < 2; ++ks) {
    thi[ks] = *(const short8*)&tbh[wave][idx15 * 72 + ks * 32 + koff];
    tlo[ks] = *(const short8*)&tbl[wave][idx15 * 72 + ks * 32 + koff];
  }

  // MLP2 (+ wave1: self GEMM); facc = partial output
  f32x4 facc[4];
#pragma unroll
  for (int cb = 0; cb < 4; ++cb) {
    int c = cb * 16 + idx15;
    float bi = b2[((size_t)l * 2 + r) * 64 + c];
    if (wave == 1) bi += selfb[l * 64 + c];
    facc[cb] = (f32x4){bi, bi, bi, bi};
  }
#pragma unroll
  for (int cb = 0; cb < 4; ++cb) {
    int c = cb * 16 + idx15;
#pragma unroll
    for (int ks = 0; ks < 2; ++ks) {
      const short8 bh = *(const short8*)&whi[WOFF(m2, c, ks)];
      const short8 bl = *(const short8*)&wlo[WOFF(m2, c, ks)];
      facc[cb] = __builtin_amdgcn_mfma_f32_16x16x32_bf16(thi[ks], bh, facc[cb], 0, 0, 0);
      facc[cb] = __builtin_amdgcn_mfma_f32_16x16x32_bf16(thi[ks], bl, facc[cb], 0, 0, 0);
      facc[cb] = __builtin_amdgcn_mfma_f32_16x16x32_bf16(tlo[ks], bh, facc[cb], 0, 0, 0);
    }
  }
  if (wave == 1) {
    short8 ahi[2], alo[2];
#pragma unroll
    for (int ks = 0; ks < 2; ++ks)
#pragma unroll
      for (int j = 0; j < 8; ++j) {
        unsigned short hb2 = bf16_rne(f[ks][j]);
        ahi[ks][j] = (short)hb2;
        alo[ks][j] = (short)bf16_rne(f[ks][j] - bf16_tof(hb2));
      }
#pragma unroll
    for (int cb = 0; cb < 4; ++cb) {
      int c = cb * 16 + idx15;
#pragma unroll
      for (int ks = 0; ks < 2; ++ks) {
        const short8 bh = *(const short8*)&whi[WOFF(0, c, ks)];
        const short8 bl = *(const short8*)&wlo[WOFF(0, c, ks)];
        facc[cb] = __builtin_amdgcn_mfma_f32_16x16x32_bf16(ahi[ks], bh, facc[cb], 0, 0, 0);
        facc[cb] = __builtin_amdgcn_mfma_f32_16x16x32_bf16(ahi[ks], bl, facc[cb], 0, 0, 0);
        facc[cb] = __builtin_amdgcn_mfma_f32_16x16x32_bf16(alo[ks], bh, facc[cb], 0, 0, 0);
      }
    }
  }
  __syncthreads();                      // all tb reads done -> safe to alias
  if (wave == 1) {
#pragma unroll
    for (int cb = 0; cb < 4; ++cb)
#pragma unroll
      for (int q = 0; q < 4; ++q)
        xfer[(kg * 4 + q) * 65 + cb * 16 + idx15] = facc[cb][q];
  }
  __syncthreads();
  if (wave == 0) {
    int nrow[4];
#pragma unroll
    for (int q = 0; q < 4; ++q) nrow[q] = nodeof[task * 16 + kg * 4 + q];
#pragma unroll
    for (int cb = 0; cb < 4; ++cb)
#pragma unroll
      for (int q = 0; q < 4; ++q) {
        int row = kg * 4 + q, col = cb * 16 + idx15;
        float v = facc[cb][q] + xfer[row * 65 + col];
        size_t o = (size_t)nrow[q] * 64 + col;
        hn[o] = v;
        hnb[o] = bf16_rne(v);
      }
  }
}

// ====== fused pool+head: wave per graph, binary-search segment, no atomics ==
__global__ __launch_bounds__(64) void k_poolhead(
    const float* __restrict__ h, const int* __restrict__ batch,
    const float* __restrict__ l1W, const float* __restrict__ l1b,
    const float* __restrict__ l2W, const float* __restrict__ l2b,
    float* __restrict__ out)
{
  int g = blockIdx.x;
  int lane = threadIdx.x;
  // [start, end) = rows of graph g (batch sorted ascending)
  int lo = 0, hi = Nn;
  while (lo < hi) { int mid = (lo + hi) >> 1; if (batch[mid] < g) lo = mid + 1; else hi = mid; }
  int start = lo;
  hi = Nn;
  while (lo < hi) { int mid = (lo + hi) >> 1; if (batch[mid] < g + 1) lo = mid + 1; else hi = mid; }
  int end = lo;

  float acc = 0.0f;
  int i = start;
  for (; i + 3 < end; i += 4) {
    float v0 = h[(size_t)i * 64 + lane];
    float v1 = h[(size_t)(i + 1) * 64 + lane];
    float v2 = h[(size_t)(i + 2) * 64 + lane];
    float v3 = h[(size_t)(i + 3) * 64 + lane];
    acc += (v0 + v1) + (v2 + v3);
  }
  for (; i < end; ++i) acc += h[(size_t)i * 64 + lane];
  float p = acc / fmaxf((float)(end - start), 1.0f);

  float t = l1b[lane];
#pragma unroll
  for (int k = 0; k < Dd; ++k)
    t += __shfl(p, k, 64) * l1W[k * Dd + lane];
  t = fmaxf(t, 0.0f);
  float o = (lane < Cc) ? l2b[lane] : 0.0f;
#pragma unroll
  for (int k = 0; k < Dd; ++k) {
    float w = (lane < Cc) ? l2W[k * Cc + lane] : 0.0f;
    o += __shfl(t, k, 64) * w;
  }
  if (lane < Cc) out[(size_t)g * Cc + lane] = o;
}

extern "C" void kernel_launch(void* const* d_in, const int* in_sizes, int n_in,
                              void* d_out, int out_size, void* d_ws, size_t ws_size,
                              hipStream_t stream)
{
  const float* x     = (const float*)d_in[0];
  const int*   ei    = (const int*)d_in[1];
  const int*   et    = (const int*)d_in[2];
  const int*   batch = (const int*)d_in[3];
  const float* selfW = (const float*)d_in[4];
  const float* selfb = (const float*)d_in[5];
  const float* eps   = (const float*)d_in[6];
  const float* W1    = (const float*)d_in[7];
  const float* b1    = (const float*)d_in[8];
  const float* W2    = (const float*)d_in[9];
  const float* b2    = (const float*)d_in[10];
  const float* l1W   = (const float*)d_in[11];
  const float* l1b   = (const float*)d_in[12];
  const float* l2W   = (const float*)d_in[13];
  const float* l2b   = (const float*)d_in[14];
  float* out = (float*)d_out;

  // ws layout:
  // buf0[N*D]f buf1[N*D]f hb0[N*D]u16 hb1[N*D]u16 wtHi/wtLo[15*4096]u16
  // counts[NR] binh[128] bincur[128] offs[NR+1] cursor[NR] btot[NB] bscan[NB]
  // elist[E] nodeof[Nn] permpos[Nn]
  float* buf0 = (float*)d_ws;
  float* buf1 = buf0 + (size_t)Nn * Dd;
  unsigned short* hb0 = (unsigned short*)(buf1 + (size_t)Nn * Dd);
  unsigned short* hb1 = hb0 + (size_t)Nn * Dd;
  unsigned short* wtHi = hb1 + (size_t)Nn * Dd;
  unsigned short* wtLo = wtHi + (size_t)Ll * 5 * 4096;
  int* counts  = (int*)(wtLo + (size_t)Ll * 5 * 4096);
  int* binh    = counts + NR;
  int* bincur  = binh + 128;
  int* offs    = bincur + 128;
  int* cursor  = offs + NR + 1;
  int* btot    = cursor + NR;
  int* bscan   = btot + NB;
  int* elist   = bscan + NB;
  int* nodeof  = elist + Ee;
  int* permpos = nodeof + Nn;

  const int* src = ei;
  const int* dst = ei + Ee;

  hipMemsetAsync(counts, 0, (size_t)(NR + 256) * sizeof(int), stream);
  k_setup<<<CVT_B + PREP_B + HIST_B, 256, 0, stream>>>(
      x, hb0, selfW, W1, W2, wtHi, wtLo, dst, et, counts);

  // degree-sorted permutation + CSR build over permuted order
  k_deghist<<<(Nn + 255) / 256, 256, 0, stream>>>(counts, binh);
  k_binscan<<<1, 128, 0, stream>>>(binh, bincur);
  k_scatterp<<<(Nn + 255) / 256, 256, 0, stream>>>(counts, bincur, nodeof, permpos);
  k_scan1<<<NB, 1024, 0, stream>>>(counts, nodeof, offs, btot);
  k_scan2<<<1, 128, 0, stream>>>(btot, bscan);
  k_scan3<<<NB, 1024, 0, stream>>>(counts, nodeof, bscan, offs, cursor);
  k_fill<<<(Ee + 255) / 256, 256, 0, stream>>>(src, dst, et, permpos, cursor, elist);

  const float* h = x;
  const unsigned short* hbc = hb0;
  float* hn = buf0;
  unsigned short* hnb = hb1;
  for (int l = 0; l < Ll; ++l) {
    k_update<<<NT, 128, 0, stream>>>(h, hbc, offs, elist, nodeof, wtHi, wtLo,
                                     selfb, eps, b1, b2, hn, hnb, l);
    h = hn;
    hbc = hnb;
    hn = (hn == buf0) ? buf1 : buf0;
    hnb = (hnb == hb0) ? hb1 : hb0;
  }
  k_poolhead<<<Gg, 64, 0, stream>>>(h, batch, l1W, l1b, l2W, l2b, out);
}

// Round 11
// 306.379 us; speedup vs baseline: 1.4747x; 1.0527x over previous
//
#include <hip/hip_runtime.h>

#define Nn 50000
#define Dd 64
#define Ee 800000
#define Ll 3
#define Rr 2
#define Gg 128
#define Cc 10
#define NR (Nn * Rr)
#define NB ((NR + 1023) / 1024)
#define NT (Nn / 16)   // 3125 tasks

// k_setup block ranges (all exact multiples of 256)
#define CVT_B  3125    // Nn*Dd/4 / 256
#define PREP_B 240     // 15*4096 / 256
#define HIST_B 3125    // Ee / 256

typedef __attribute__((ext_vector_type(8))) short short8;
typedef __attribute__((ext_vector_type(4))) float f32x4;

__device__ __forceinline__ unsigned short bf16_rne(float x) {
  unsigned u = __float_as_uint(x);
  unsigned r = u + 0x7fffu + ((u >> 16) & 1u);
  return (unsigned short)(r >> 16);
}
__device__ __forceinline__ float bf16_tof(unsigned short b) {
  return __uint_as_float(((unsigned)b) << 16);
}
// accumulate 8 bf16 (packed in uint4) into z[0..7], f32
__device__ __forceinline__ void acc8(float* z, uint4 u) {
  z[0] += __uint_as_float(u.x << 16);
  z[1] += __uint_as_float(u.x & 0xffff0000u);
  z[2] += __uint_as_float(u.y << 16);
  z[3] += __uint_as_float(u.y & 0xffff0000u);
  z[4] += __uint_as_float(u.z << 16);
  z[5] += __uint_as_float(u.z & 0xffff0000u);
  z[6] += __uint_as_float(u.w << 16);
  z[7] += __uint_as_float(u.w & 0xffff0000u);
}

// ========== fused setup: x->bf16 shadow | weight split-bf16 prep | hist =====
__global__ __launch_bounds__(256) void k_setup(
    const float* __restrict__ x, unsigned short* __restrict__ hb,
    const float* __restrict__ selfW, const float* __restrict__ W1,
    const float* __restrict__ W2, unsigned short* __restrict__ wtHi,
    unsigned short* __restrict__ wtLo,
    const int* __restrict__ dst, const int* __restrict__ et,
    int* __restrict__ counts)
{
  int b = blockIdx.x;
  if (b < CVT_B) {
    int i = b * 256 + threadIdx.x;            // < 800000 exactly
    const float4 v = *(const float4*)&x[(size_t)i * 4];
    ushort4 o;
    o.x = bf16_rne(v.x); o.y = bf16_rne(v.y);
    o.z = bf16_rne(v.z); o.w = bf16_rne(v.w);
    *(ushort4*)&hb[(size_t)i * 4] = o;
  } else if (b < CVT_B + PREP_B) {
    int i = (b - CVT_B) * 256 + threadIdx.x;  // < 61440 exactly
    int l = i / (5 * 4096);
    int rem = i - l * 5 * 4096;
    int m = rem >> 12;
    int e = rem & 4095;
    int k = e >> 6, c = e & 63;
    const float* p;
    if (m == 0)      p = selfW + (size_t)l * 4096;
    else if (m == 1) p = W1 + ((size_t)l * 2 + 0) * 4096;
    else if (m == 2) p = W2 + ((size_t)l * 2 + 0) * 4096;
    else if (m == 3) p = W1 + ((size_t)l * 2 + 1) * 4096;
    else             p = W2 + ((size_t)l * 2 + 1) * 4096;
    float w = p[e];
    unsigned short hi = bf16_rne(w);
    unsigned short lo = bf16_rne(w - bf16_tof(hi));
    size_t o = ((size_t)(l * 5 + m) * 64 + c) * 64 + k;
    wtHi[o] = hi;
    wtLo[o] = lo;
  } else {
    int e = (b - CVT_B - PREP_B) * 256 + threadIdx.x;  // < Ee exactly
    atomicAdd(&counts[et[e] * Nn + dst[e]], 1);
  }
}

// ================= CSR scan + fill ==========================================
__global__ __launch_bounds__(1024) void k_scan1(
    const int* __restrict__ counts, int* __restrict__ offs,
    int* __restrict__ btot)
{
  __shared__ int s[1024];
  int i = blockIdx.x * 1024 + threadIdx.x;
  int v = (i < NR) ? counts[i] : 0;
  s[threadIdx.x] = v;
  __syncthreads();
#pragma unroll
  for (int d = 1; d < 1024; d <<= 1) {
    int t = (threadIdx.x >= d) ? s[threadIdx.x - d] : 0;
    __syncthreads();
    s[threadIdx.x] += t;
    __syncthreads();
  }
  if (i < NR) offs[i + 1] = s[threadIdx.x];
  if (threadIdx.x == 1023) btot[blockIdx.x] = s[1023];
}

__global__ __launch_bounds__(128) void k_scan2(
    const int* __restrict__ btot, int* __restrict__ bscan)
{
  __shared__ int s[128];
  int v = (threadIdx.x < NB) ? btot[threadIdx.x] : 0;
  s[threadIdx.x] = v;
  __syncthreads();
#pragma unroll
  for (int d = 1; d < 128; d <<= 1) {
    int t = (threadIdx.x >= d) ? s[threadIdx.x - d] : 0;
    __syncthreads();
    s[threadIdx.x] += t;
    __syncthreads();
  }
  if (threadIdx.x < NB) bscan[threadIdx.x] = s[threadIdx.x] - v;  // exclusive
}

__global__ __launch_bounds__(1024) void k_scan3(
    const int* __restrict__ counts, const int* __restrict__ bscan,
    int* __restrict__ offs, int* __restrict__ cursor)
{
  int i = blockIdx.x * 1024 + threadIdx.x;
  if (i >= NR) return;
  int o = offs[i + 1] + bscan[blockIdx.x];
  offs[i + 1] = o;
  cursor[i] = o - counts[i];
  if (i == 0) offs[0] = 0;
}

__global__ __launch_bounds__(256) void k_fill(
    const int* __restrict__ src, const int* __restrict__ dst,
    const int* __restrict__ et, int* __restrict__ cursor,
    int* __restrict__ elist)
{
  int e = blockIdx.x * 256 + threadIdx.x;
  if (e >= Ee) return;
  int pos = atomicAdd(&cursor[et[e] * Nn + dst[e]], 1);
  elist[pos] = src[e];
}

// ====== fused per-layer update: (task, relation) per wave + LDS combine =====
// Gather is two-phase by 64-B line parity: phase A touches only low lines
// (features 0..31) of all rows in the list, phase B only high lines. The
// chip-wide working set per phase is 3.2 MB -> fits per-XCD L2.
#define WOFF(m, c, ks) ((size_t)(m)*4096 + (size_t)(c)*64 + (ks)*32 + koff)

__global__ __launch_bounds__(128, 5) void k_update(
    const float* __restrict__ h, const unsigned short* __restrict__ hb,
    const int* __restrict__ offs, const int* __restrict__ elist,
    const unsigned short* __restrict__ wtHi, const unsigned short* __restrict__ wtLo,
    const float* __restrict__ selfb, const float* __restrict__ eps,
    const float* __restrict__ b1, const float* __restrict__ b2,
    float* __restrict__ hn, unsigned short* __restrict__ hnb, int l)
{
  __shared__ __align__(16) unsigned short tbh[2][16 * 72];  // 4608 B
  __shared__ __align__(16) unsigned short tbl[2][16 * 72];  // 4608 B
  float* xfer = (float*)&tbh[0][0];     // aliased: tb dead by combine time
  const int wave = threadIdx.x >> 6;    // = relation r
  const int lane = threadIdx.x & 63;
  const int task = blockIdx.x;
  const int r = wave;
  const int idx15 = lane & 15;
  const int kg = lane >> 4;
  const int koff = kg * 8;
  const int nodeA = task * 16 + idx15;

  // h row fragment (row = idx15, features koff..koff+7 per kstep), f32
  float f[2][8];
  {
    const float* hp = &h[(size_t)nodeA * 64 + koff];
    const float4 a0 = *(const float4*)(hp);
    const float4 a1 = *(const float4*)(hp + 4);
    const float4 b0 = *(const float4*)(hp + 32);
    const float4 b1v = *(const float4*)(hp + 36);
    f[0][0] = a0.x; f[0][1] = a0.y; f[0][2] = a0.z; f[0][3] = a0.w;
    f[0][4] = a1.x; f[0][5] = a1.y; f[0][6] = a1.z; f[0][7] = a1.w;
    f[1][0] = b0.x; f[1][1] = b0.y; f[1][2] = b0.z; f[1][3] = b0.w;
    f[1][4] = b1v.x; f[1][5] = b1v.y; f[1][6] = b1v.z; f[1][7] = b1v.w;
  }

  const unsigned short* whi = wtHi + (size_t)l * 5 * 4096;
  const unsigned short* wlo = wtLo + (size_t)l * 5 * 4096;
  const int m1 = 1 + 2 * r, m2 = 2 + 2 * r;
  const float er = 1.0f + eps[l * Rr + r];

  // ---- two-phase CSR gather, 8-deep pipelined per phase ---------------------
  float za[2][8];
#pragma unroll
  for (int ks = 0; ks < 2; ++ks)
#pragma unroll
    for (int jj = 0; jj < 8; ++jj) za[ks][jj] = 0.0f;
  {
    const int aidx = r * Nn + nodeA;
    const int jb = offs[aidx], je = offs[aidx + 1];
#pragma unroll
    for (int ph = 0; ph < 2; ++ph) {
      const int fo = ph * 32 + koff;        // line parity: ph=0 low, ph=1 high
      int j = jb;
      for (; j + 7 < je; j += 8) {
        int s0 = elist[j],     s1 = elist[j + 1];
        int s2 = elist[j + 2], s3 = elist[j + 3];
        int s4 = elist[j + 4], s5 = elist[j + 5];
        int s6 = elist[j + 6], s7 = elist[j + 7];
        const uint4 a0 = *(const uint4*)&hb[(size_t)s0 * 64 + fo];
        const uint4 a1 = *(const uint4*)&hb[(size_t)s1 * 64 + fo];
        const uint4 a2 = *(const uint4*)&hb[(size_t)s2 * 64 + fo];
        const uint4 a3 = *(const uint4*)&hb[(size_t)s3 * 64 + fo];
        const uint4 a4 = *(const uint4*)&hb[(size_t)s4 * 64 + fo];
        const uint4 a5 = *(const uint4*)&hb[(size_t)s5 * 64 + fo];
        const uint4 a6 = *(const uint4*)&hb[(size_t)s6 * 64 + fo];
        const uint4 a7 = *(const uint4*)&hb[(size_t)s7 * 64 + fo];
        acc8(za[ph], a0); acc8(za[ph], a1); acc8(za[ph], a2); acc8(za[ph], a3);
        acc8(za[ph], a4); acc8(za[ph], a5); acc8(za[ph], a6); acc8(za[ph], a7);
      }
      if (j + 3 < je) {
        int s0 = elist[j],     s1 = elist[j + 1];
        int s2 = elist[j + 2], s3 = elist[j + 3];
        const uint4 a0 = *(const uint4*)&hb[(size_t)s0 * 64 + fo];
        const uint4 a1 = *(const uint4*)&hb[(size_t)s1 * 64 + fo];
        const uint4 a2 = *(const uint4*)&hb[(size_t)s2 * 64 + fo];
        const uint4 a3 = *(const uint4*)&hb[(size_t)s3 * 64 + fo];
        acc8(za[ph], a0); acc8(za[ph], a1); acc8(za[ph], a2); acc8(za[ph], a3);
        j += 4;
      }
      for (; j < je; ++j)
        acc8(za[ph], *(const uint4*)&hb[(size_t)elist[j] * 64 + fo]);
    }
  }

  // z = er*h + za -> split bf16
  short8 zhi[2], zlo[2];
#pragma unroll
  for (int ks = 0; ks < 2; ++ks)
#pragma unroll
    for (int jj = 0; jj < 8; ++jj) {
      float zf = er * f[ks][jj] + za[ks][jj];
      unsigned short hb2 = bf16_rne(zf);
      zhi[ks][jj] = (short)hb2;
      zlo[ks][jj] = (short)bf16_rne(zf - bf16_tof(hb2));
    }

  // MLP1: tacc = relu(z @ W1_r + b1_r)
  f32x4 tacc[4];
#pragma unroll
  for (int cb = 0; cb < 4; ++cb) {
    float bi = b1[((size_t)l * 2 + r) * 64 + cb * 16 + idx15];
    tacc[cb] = (f32x4){bi, bi, bi, bi};
  }
#pragma unroll
  for (int cb = 0; cb < 4; ++cb) {
    int c = cb * 16 + idx15;
#pragma unroll
    for (int ks = 0; ks < 2; ++ks) {
      const short8 bh = *(const short8*)&whi[WOFF(m1, c, ks)];
      const short8 bl = *(const short8*)&wlo[WOFF(m1, c, ks)];
      tacc[cb] = __builtin_amdgcn_mfma_f32_16x16x32_bf16(zhi[ks], bh, tacc[cb], 0, 0, 0);
      tacc[cb] = __builtin_amdgcn_mfma_f32_16x16x32_bf16(zhi[ks], bl, tacc[cb], 0, 0, 0);
      tacc[cb] = __builtin_amdgcn_mfma_f32_16x16x32_bf16(zlo[ks], bh, tacc[cb], 0, 0, 0);
    }
  }
  // relu -> split-bf16 -> LDS transpose bounce (per-wave buffer, no barrier)
#pragma unroll
  for (int cb = 0; cb < 4; ++cb)
#pragma unroll
    for (int q = 0; q < 4; ++q) {
      float tv = fmaxf(tacc[cb][q], 0.0f);
      unsigned short hb2 = bf16_rne(tv);
      tbh[wave][(kg * 4 + q) * 72 + cb * 16 + idx15] = hb2;
      tbl[wave][(kg * 4 + q) * 72 + cb * 16 + idx15] = bf16_rne(tv - bf16_tof(hb2));
    }
  asm volatile("s_waitcnt lgkmcnt(0)" ::: "memory");
  __builtin_amdgcn_sched_barrier(0);
  short8 thi[2], tlo[2];
#pragma unroll
  for (int ks = 0; ks < 2; ++ks) {
    thi[ks] = *(const short8*)&tbh[wave][idx15 * 72 + ks * 32 + koff];
    tlo[ks] = *(const short8*)&tbl[wave][idx15 * 72 + ks * 32 + koff];
  }

  // MLP2 (+ wave1: self GEMM); facc = partial output
  f32x4 facc[4];
#pragma unroll
  for (int cb = 0; cb < 4; ++cb) {
    int c = cb * 16 + idx15;
    float bi = b2[((size_t)l * 2 + r) * 64 + c];
    if (wave == 1) bi += selfb[l * 64 + c];
    facc[cb] = (f32x4){bi, bi, bi, bi};
  }
#pragma unroll
  for (int cb = 0; cb < 4; ++cb) {
    int c = cb * 16 + idx15;
#pragma unroll
    for (int ks = 0; ks < 2; ++ks) {
      const short8 bh = *(const short8*)&whi[WOFF(m2, c, ks)];
      const short8 bl = *(const short8*)&wlo[WOFF(m2, c, ks)];
      facc[cb] = __builtin_amdgcn_mfma_f32_16x16x32_bf16(thi[ks], bh, facc[cb], 0, 0, 0);
      facc[cb] = __builtin_amdgcn_mfma_f32_16x16x32_bf16(thi[ks], bl, facc[cb], 0, 0, 0);
      facc[cb] = __builtin_amdgcn_mfma_f32_16x16x32_bf16(tlo[ks], bh, facc[cb], 0, 0, 0);
    }
  }
  if (wave == 1) {
    short8 ahi[2], alo[2];
#pragma unroll
    for (int ks = 0; ks < 2; ++ks)
#pragma unroll
      for (int jj = 0; jj < 8; ++jj) {
        unsigned short hb2 = bf16_rne(f[ks][jj]);
        ahi[ks][jj] = (short)hb2;
        alo[ks][jj] = (short)bf16_rne(f[ks][jj] - bf16_tof(hb2));
      }
#pragma unroll
    for (int cb = 0; cb < 4; ++cb) {
      int c = cb * 16 + idx15;
#pragma unroll
      for (int ks = 0; ks < 2; ++ks) {
        const short8 bh = *(const short8*)&whi[WOFF(0, c, ks)];
        const short8 bl = *(const short8*)&wlo[WOFF(0, c, ks)];
        facc[cb] = __builtin_amdgcn_mfma_f32_16x16x32_bf16(ahi[ks], bh, facc[cb], 0, 0, 0);
        facc[cb] = __builtin_amdgcn_mfma_f32_16x16x32_bf16(ahi[ks], bl, facc[cb], 0, 0, 0);
        facc[cb] = __builtin_amdgcn_mfma_f32_16x16x32_bf16(alo[ks], bh, facc[cb], 0, 0, 0);
      }
    }
  }
  __syncthreads();                      // all tb reads done -> safe to alias
  if (wave == 1) {
#pragma unroll
    for (int cb = 0; cb < 4; ++cb)
#pragma unroll
      for (int q = 0; q < 4; ++q)
        xfer[(kg * 4 + q) * 65 + cb * 16 + idx15] = facc[cb][q];
  }
  __syncthreads();
  if (wave == 0) {
#pragma unroll
    for (int cb = 0; cb < 4; ++cb)
#pragma unroll
      for (int q = 0; q < 4; ++q) {
        int row = kg * 4 + q, col = cb * 16 + idx15;
        float v = facc[cb][q] + xfer[row * 65 + col];
        size_t o = ((size_t)task * 16 + row) * 64 + col;
        hn[o] = v;
        hnb[o] = bf16_rne(v);
      }
  }
}

// ====== fused pool+head: wave per graph, binary-search segment, no atomics ==
__global__ __launch_bounds__(64) void k_poolhead(
    const float* __restrict__ h, const int* __restrict__ batch,
    const float* __restrict__ l1W, const float* __restrict__ l1b,
    const float* __restrict__ l2W, const float* __restrict__ l2b,
    float* __restrict__ out)
{
  int g = blockIdx.x;
  int lane = threadIdx.x;
  // [start, end) = rows of graph g (batch sorted ascending)
  int lo = 0, hi = Nn;
  while (lo < hi) { int mid = (lo + hi) >> 1; if (batch[mid] < g) lo = mid + 1; else hi = mid; }
  int start = lo;
  hi = Nn;
  while (lo < hi) { int mid = (lo + hi) >> 1; if (batch[mid] < g + 1) lo = mid + 1; else hi = mid; }
  int end = lo;

  float acc = 0.0f;
  int i = start;
  for (; i + 3 < end; i += 4) {
    float v0 = h[(size_t)i * 64 + lane];
    float v1 = h[(size_t)(i + 1) * 64 + lane];
    float v2 = h[(size_t)(i + 2) * 64 + lane];
    float v3 = h[(size_t)(i + 3) * 64 + lane];
    acc += (v0 + v1) + (v2 + v3);
  }
  for (; i < end; ++i) acc += h[(size_t)i * 64 + lane];
  float p = acc / fmaxf((float)(end - start), 1.0f);

  float t = l1b[lane];
#pragma unroll
  for (int k = 0; k < Dd; ++k)
    t += __shfl(p, k, 64) * l1W[k * Dd + lane];
  t = fmaxf(t, 0.0f);
  float o = (lane < Cc) ? l2b[lane] : 0.0f;
#pragma unroll
  for (int k = 0; k < Dd; ++k) {
    float w = (lane < Cc) ? l2W[k * Cc + lane] : 0.0f;
    o += __shfl(t, k, 64) * w;
  }
  if (lane < Cc) out[(size_t)g * Cc + lane] = o;
}

extern "C" void kernel_launch(void* const* d_in, const int* in_sizes, int n_in,
                              void* d_out, int out_size, void* d_ws, size_t ws_size,
                              hipStream_t stream)
{
  const float* x     = (const float*)d_in[0];
  const int*   ei    = (const int*)d_in[1];
  const int*   et    = (const int*)d_in[2];
  const int*   batch = (const int*)d_in[3];
  const float* selfW = (const float*)d_in[4];
  const float* selfb = (const float*)d_in[5];
  const float* eps   = (const float*)d_in[6];
  const float* W1    = (const float*)d_in[7];
  const float* b1    = (const float*)d_in[8];
  const float* W2    = (const float*)d_in[9];
  const float* b2    = (const float*)d_in[10];
  const float* l1W   = (const float*)d_in[11];
  const float* l1b   = (const float*)d_in[12];
  const float* l2W   = (const float*)d_in[13];
  const float* l2b   = (const float*)d_in[14];
  float* out = (float*)d_out;

  // ws layout:
  // buf0[N*D]f buf1[N*D]f hb0[N*D]u16 hb1[N*D]u16
  // wtHi/wtLo[15*4096]u16 counts[NR] offs[NR+1] cursor[NR] btot[NB] bscan[NB] elist[E]
  float* buf0 = (float*)d_ws;
  float* buf1 = buf0 + (size_t)Nn * Dd;
  unsigned short* hb0 = (unsigned short*)(buf1 + (size_t)Nn * Dd);
  unsigned short* hb1 = hb0 + (size_t)Nn * Dd;
  unsigned short* wtHi = hb1 + (size_t)Nn * Dd;
  unsigned short* wtLo = wtHi + (size_t)Ll * 5 * 4096;
  int* counts = (int*)(wtLo + (size_t)Ll * 5 * 4096);
  int* offs   = counts + NR;
  int* cursor = offs + NR + 1;
  int* btot   = cursor + NR;
  int* bscan  = btot + NB;
  int* elist  = bscan + NB;

  const int* src = ei;
  const int* dst = ei + Ee;

  hipMemsetAsync(counts, 0, (size_t)NR * sizeof(int), stream);
  k_setup<<<CVT_B + PREP_B + HIST_B, 256, 0, stream>>>(
      x, hb0, selfW, W1, W2, wtHi, wtLo, dst, et, counts);

  // CSR build (graph static across layers)
  k_scan1<<<NB, 1024, 0, stream>>>(counts, offs, btot);
  k_scan2<<<1, 128, 0, stream>>>(btot, bscan);
  k_scan3<<<NB, 1024, 0, stream>>>(counts, bscan, offs, cursor);
  k_fill<<<(Ee + 255) / 256, 256, 0, stream>>>(src, dst, et, cursor, elist);

  const float* h = x;
  const unsigned short* hbc = hb0;
  float* hn = buf0;
  unsigned short* hnb = hb1;
  for (int l = 0; l < Ll; ++l) {
    k_update<<<NT, 128, 0, stream>>>(h, hbc, offs, elist, wtHi, wtLo,
                                     selfb, eps, b1, b2, hn, hnb, l);
    h = hn;
    hbc = hnb;
    hn = (hn == buf0) ? buf1 : buf0;
    hnb = (hnb == hb0) ? hb1 : hb0;
  }
  k_poolhead<<<Gg, 64, 0, stream>>>(h, batch, l1W, l1b, l2W, l2b, out);
}

// Round 12
// 296.455 us; speedup vs baseline: 1.5241x; 1.0335x over previous
//
#include <hip/hip_runtime.h>

#define Nn 50000
#define Dd 64
#define Ee 800000
#define Ll 3
#define Rr 2
#define Gg 128
#define Cc 10
#define NR (Nn * Rr)
#define NB ((NR + 1023) / 1024)
#define NT (Nn / 16)   // 3125 tasks
#define EPAD (Ee + 4 * NR + 64)   // padded elist capacity

// k_setup block ranges (all exact multiples of 256)
#define CVT_B  3125    // Nn*Dd/4 / 256
#define PREP_B 240     // 15*4096 / 256
#define HIST_B 3125    // Ee / 256

typedef __attribute__((ext_vector_type(8))) short short8;
typedef __attribute__((ext_vector_type(4))) float f32x4;

__device__ __forceinline__ unsigned short bf16_rne(float x) {
  unsigned u = __float_as_uint(x);
  unsigned r = u + 0x7fffu + ((u >> 16) & 1u);
  return (unsigned short)(r >> 16);
}
__device__ __forceinline__ float bf16_tof(unsigned short b) {
  return __uint_as_float(((unsigned)b) << 16);
}
// accumulate 8 bf16 (packed in uint4) into z[0..7], f32
__device__ __forceinline__ void acc8(float* z, uint4 u) {
  z[0] += __uint_as_float(u.x << 16);
  z[1] += __uint_as_float(u.x & 0xffff0000u);
  z[2] += __uint_as_float(u.y << 16);
  z[3] += __uint_as_float(u.y & 0xffff0000u);
  z[4] += __uint_as_float(u.z << 16);
  z[5] += __uint_as_float(u.z & 0xffff0000u);
  z[6] += __uint_as_float(u.w << 16);
  z[7] += __uint_as_float(u.w & 0xffff0000u);
}

// ========== fused setup: x->bf16 shadow | weight split-bf16 prep | hist =====
__global__ __launch_bounds__(256) void k_setup(
    const float* __restrict__ x, unsigned short* __restrict__ hb,
    const float* __restrict__ selfW, const float* __restrict__ W1,
    const float* __restrict__ W2, unsigned short* __restrict__ wtHi,
    unsigned short* __restrict__ wtLo,
    const int* __restrict__ dst, const int* __restrict__ et,
    int* __restrict__ counts)
{
  int b = blockIdx.x;
  if (b < CVT_B) {
    int i = b * 256 + threadIdx.x;            // < 800000 exactly
    const float4 v = *(const float4*)&x[(size_t)i * 4];
    ushort4 o;
    o.x = bf16_rne(v.x); o.y = bf16_rne(v.y);
    o.z = bf16_rne(v.z); o.w = bf16_rne(v.w);
    *(ushort4*)&hb[(size_t)i * 4] = o;
  } else if (b < CVT_B + PREP_B) {
    int i = (b - CVT_B) * 256 + threadIdx.x;  // < 61440 exactly
    int l = i / (5 * 4096);
    int rem = i - l * 5 * 4096;
    int m = rem >> 12;
    int e = rem & 4095;
    int k = e >> 6, c = e & 63;
    const float* p;
    if (m == 0)      p = selfW + (size_t)l * 4096;
    else if (m == 1) p = W1 + ((size_t)l * 2 + 0) * 4096;
    else if (m == 2) p = W2 + ((size_t)l * 2 + 0) * 4096;
    else if (m == 3) p = W1 + ((size_t)l * 2 + 1) * 4096;
    else             p = W2 + ((size_t)l * 2 + 1) * 4096;
    float w = p[e];
    unsigned short hi = bf16_rne(w);
    unsigned short lo = bf16_rne(w - bf16_tof(hi));
    size_t o = ((size_t)(l * 5 + m) * 64 + c) * 64 + k;
    wtHi[o] = hi;
    wtLo[o] = lo;
  } else {
    int e = (b - CVT_B - PREP_B) * 256 + threadIdx.x;  // < Ee exactly
    atomicAdd(&counts[et[e] * Nn + dst[e]], 1);
  }
}

// ================= CSR scan + fill (segments padded to 4-int multiples) =====
__global__ __launch_bounds__(1024) void k_scan1(
    const int* __restrict__ counts, int* __restrict__ offs,
    int* __restrict__ btot)
{
  __shared__ int s[1024];
  int i = blockIdx.x * 1024 + threadIdx.x;
  int v = (i < NR) ? ((counts[i] + 3) & ~3) : 0;   // padded count
  s[threadIdx.x] = v;
  __syncthreads();
#pragma unroll
  for (int d = 1; d < 1024; d <<= 1) {
    int t = (threadIdx.x >= d) ? s[threadIdx.x - d] : 0;
    __syncthreads();
    s[threadIdx.x] += t;
    __syncthreads();
  }
  if (i < NR) offs[i + 1] = s[threadIdx.x];
  if (threadIdx.x == 1023) btot[blockIdx.x] = s[1023];
}

__global__ __launch_bounds__(128) void k_scan2(
    const int* __restrict__ btot, int* __restrict__ bscan)
{
  __shared__ int s[128];
  int v = (threadIdx.x < NB) ? btot[threadIdx.x] : 0;
  s[threadIdx.x] = v;
  __syncthreads();
#pragma unroll
  for (int d = 1; d < 128; d <<= 1) {
    int t = (threadIdx.x >= d) ? s[threadIdx.x - d] : 0;
    __syncthreads();
    s[threadIdx.x] += t;
    __syncthreads();
  }
  if (threadIdx.x < NB) bscan[threadIdx.x] = s[threadIdx.x] - v;  // exclusive
}

__global__ __launch_bounds__(1024) void k_scan3(
    const int* __restrict__ counts, const int* __restrict__ bscan,
    int* __restrict__ offs, int* __restrict__ cursor)
{
  int i = blockIdx.x * 1024 + threadIdx.x;
  if (i >= NR) return;
  int o = offs[i + 1] + bscan[blockIdx.x];
  offs[i + 1] = o;
  cursor[i] = o - ((counts[i] + 3) & ~3);   // 16B-aligned segment start
  if (i == 0) offs[0] = 0;
}

__global__ __launch_bounds__(256) void k_fill(
    const int* __restrict__ src, const int* __restrict__ dst,
    const int* __restrict__ et, int* __restrict__ cursor,
    int* __restrict__ elist)
{
  int e = blockIdx.x * 256 + threadIdx.x;
  if (e >= Ee) return;
  int pos = atomicAdd(&cursor[et[e] * Nn + dst[e]], 1);
  elist[pos] = src[e];
}

// ====== fused per-layer update: (task, relation) per wave + LDS combine =====
// Gather: 4-deep row pipeline + int4 elist prefetch (software pipelined so
// row addresses never wait on the edge-index load).
#define WOFF(m, c, ks) ((size_t)(m)*4096 + (size_t)(c)*64 + (ks)*32 + koff)

__global__ __launch_bounds__(128, 5) void k_update(
    const float* __restrict__ h, const unsigned short* __restrict__ hb,
    const int* __restrict__ offs, const int* __restrict__ counts,
    const int* __restrict__ elist,
    const unsigned short* __restrict__ wtHi, const unsigned short* __restrict__ wtLo,
    const float* __restrict__ selfb, const float* __restrict__ eps,
    const float* __restrict__ b1, const float* __restrict__ b2,
    float* __restrict__ hn, unsigned short* __restrict__ hnb, int l)
{
  __shared__ __align__(16) unsigned short tbh[2][16 * 72];  // 4608 B
  __shared__ __align__(16) unsigned short tbl[2][16 * 72];  // 4608 B
  float* xfer = (float*)&tbh[0][0];     // aliased: tb dead by combine time
  const int wave = threadIdx.x >> 6;    // = relation r
  const int lane = threadIdx.x & 63;
  const int task = blockIdx.x;
  const int r = wave;
  const int idx15 = lane & 15;
  const int kg = lane >> 4;
  const int koff = kg * 8;
  const int nodeA = task * 16 + idx15;

  // h row fragment (row = idx15, features koff..koff+7 per kstep), f32
  float f[2][8];
  {
    const float* hp = &h[(size_t)nodeA * 64 + koff];
    const float4 a0 = *(const float4*)(hp);
    const float4 a1 = *(const float4*)(hp + 4);
    const float4 b0 = *(const float4*)(hp + 32);
    const float4 b1v = *(const float4*)(hp + 36);
    f[0][0] = a0.x; f[0][1] = a0.y; f[0][2] = a0.z; f[0][3] = a0.w;
    f[0][4] = a1.x; f[0][5] = a1.y; f[0][6] = a1.z; f[0][7] = a1.w;
    f[1][0] = b0.x; f[1][1] = b0.y; f[1][2] = b0.z; f[1][3] = b0.w;
    f[1][4] = b1v.x; f[1][5] = b1v.y; f[1][6] = b1v.z; f[1][7] = b1v.w;
  }

  const unsigned short* whi = wtHi + (size_t)l * 5 * 4096;
  const unsigned short* wlo = wtLo + (size_t)l * 5 * 4096;
  const int m1 = 1 + 2 * r, m2 = 2 + 2 * r;
  const float er = 1.0f + eps[l * Rr + r];

  // ---- CSR gather: int4-prefetched, 4 row-pairs in flight -------------------
  float za[2][8];
#pragma unroll
  for (int ks = 0; ks < 2; ++ks)
#pragma unroll
    for (int jj = 0; jj < 8; ++jj) za[ks][jj] = 0.0f;
  {
    const int aidx = r * Nn + nodeA;
    const int jb = offs[aidx];            // 16B-aligned
    const int je = jb + counts[aidx];
    int j = jb;
    if (j + 3 < je) {
      int4 ec = *(const int4*)&elist[j];  // prologue (padded region: safe)
      for (; j + 3 < je; j += 4) {
        int4 en = *(const int4*)&elist[j + 4];   // prefetch next (padded: safe)
        const unsigned short* q0 = &hb[(size_t)ec.x * 64 + koff];
        const unsigned short* q1 = &hb[(size_t)ec.y * 64 + koff];
        const unsigned short* q2 = &hb[(size_t)ec.z * 64 + koff];
        const unsigned short* q3 = &hb[(size_t)ec.w * 64 + koff];
        const uint4 a0 = *(const uint4*)(q0);
        const uint4 a1 = *(const uint4*)(q1);
        const uint4 a2 = *(const uint4*)(q2);
        const uint4 a3 = *(const uint4*)(q3);
        const uint4 b0 = *(const uint4*)(q0 + 32);
        const uint4 b1q = *(const uint4*)(q1 + 32);
        const uint4 b2q = *(const uint4*)(q2 + 32);
        const uint4 b3 = *(const uint4*)(q3 + 32);
        acc8(za[0], a0); acc8(za[0], a1); acc8(za[0], a2); acc8(za[0], a3);
        acc8(za[1], b0); acc8(za[1], b1q); acc8(za[1], b2q); acc8(za[1], b3);
        ec = en;
      }
    }
    for (; j < je; ++j) {
      const unsigned short* q = &hb[(size_t)elist[j] * 64 + koff];
      const uint4 a = *(const uint4*)(q);
      const uint4 b = *(const uint4*)(q + 32);
      acc8(za[0], a); acc8(za[1], b);
    }
  }

  // z = er*h + za -> split bf16
  short8 zhi[2], zlo[2];
#pragma unroll
  for (int ks = 0; ks < 2; ++ks)
#pragma unroll
    for (int jj = 0; jj < 8; ++jj) {
      float zf = er * f[ks][jj] + za[ks][jj];
      unsigned short hb2 = bf16_rne(zf);
      zhi[ks][jj] = (short)hb2;
      zlo[ks][jj] = (short)bf16_rne(zf - bf16_tof(hb2));
    }

  // MLP1: tacc = relu(z @ W1_r + b1_r)
  f32x4 tacc[4];
#pragma unroll
  for (int cb = 0; cb < 4; ++cb) {
    float bi = b1[((size_t)l * 2 + r) * 64 + cb * 16 + idx15];
    tacc[cb] = (f32x4){bi, bi, bi, bi};
  }
#pragma unroll
  for (int cb = 0; cb < 4; ++cb) {
    int c = cb * 16 + idx15;
#pragma unroll
    for (int ks = 0; ks < 2; ++ks) {
      const short8 bh = *(const short8*)&whi[WOFF(m1, c, ks)];
      const short8 bl = *(const short8*)&wlo[WOFF(m1, c, ks)];
      tacc[cb] = __builtin_amdgcn_mfma_f32_16x16x32_bf16(zhi[ks], bh, tacc[cb], 0, 0, 0);
      tacc[cb] = __builtin_amdgcn_mfma_f32_16x16x32_bf16(zhi[ks], bl, tacc[cb], 0, 0, 0);
      tacc[cb] = __builtin_amdgcn_mfma_f32_16x16x32_bf16(zlo[ks], bh, tacc[cb], 0, 0, 0);
    }
  }
  // relu -> split-bf16 -> LDS transpose bounce (per-wave buffer, no barrier)
#pragma unroll
  for (int cb = 0; cb < 4; ++cb)
#pragma unroll
    for (int q = 0; q < 4; ++q) {
      float tv = fmaxf(tacc[cb][q], 0.0f);
      unsigned short hb2 = bf16_rne(tv);
      tbh[wave][(kg * 4 + q) * 72 + cb * 16 + idx15] = hb2;
      tbl[wave][(kg * 4 + q) * 72 + cb * 16 + idx15] = bf16_rne(tv - bf16_tof(hb2));
    }
  asm volatile("s_waitcnt lgkmcnt(0)" ::: "memory");
  __builtin_amdgcn_sched_barrier(0);
  short8 thi[2], tlo[2];
#pragma unroll
  for (int ks = 0; ks < 2; ++ks) {
    thi[ks] = *(const short8*)&tbh[wave][idx15 * 72 + ks * 32 + koff];
    tlo[ks] = *(const short8*)&tbl[wave][idx15 * 72 + ks * 32 + koff];
  }

  // MLP2 (+ wave1: self GEMM); facc = partial output
  f32x4 facc[4];
#pragma unroll
  for (int cb = 0; cb < 4; ++cb) {
    int c = cb * 16 + idx15;
    float bi = b2[((size_t)l * 2 + r) * 64 + c];
    if (wave == 1) bi += selfb[l * 64 + c];
    facc[cb] = (f32x4){bi, bi, bi, bi};
  }
#pragma unroll
  for (int cb = 0; cb < 4; ++cb) {
    int c = cb * 16 + idx15;
#pragma unroll
    for (int ks = 0; ks < 2; ++ks) {
      const short8 bh = *(const short8*)&whi[WOFF(m2, c, ks)];
      const short8 bl = *(const short8*)&wlo[WOFF(m2, c, ks)];
      facc[cb] = __builtin_amdgcn_mfma_f32_16x16x32_bf16(thi[ks], bh, facc[cb], 0, 0, 0);
      facc[cb] = __builtin_amdgcn_mfma_f32_16x16x32_bf16(thi[ks], bl, facc[cb], 0, 0, 0);
      facc[cb] = __builtin_amdgcn_mfma_f32_16x16x32_bf16(tlo[ks], bh, facc[cb], 0, 0, 0);
    }
  }
  if (wave == 1) {
    short8 ahi[2], alo[2];
#pragma unroll
    for (int ks = 0; ks < 2; ++ks)
#pragma unroll
      for (int jj = 0; jj < 8; ++jj) {
        unsigned short hb2 = bf16_rne(f[ks][jj]);
        ahi[ks][jj] = (short)hb2;
        alo[ks][jj] = (short)bf16_rne(f[ks][jj] - bf16_tof(hb2));
      }
#pragma unroll
    for (int cb = 0; cb < 4; ++cb) {
      int c = cb * 16 + idx15;
#pragma unroll
      for (int ks = 0; ks < 2; ++ks) {
        const short8 bh = *(const short8*)&whi[WOFF(0, c, ks)];
        const short8 bl = *(const short8*)&wlo[WOFF(0, c, ks)];
        facc[cb] = __builtin_amdgcn_mfma_f32_16x16x32_bf16(ahi[ks], bh, facc[cb], 0, 0, 0);
        facc[cb] = __builtin_amdgcn_mfma_f32_16x16x32_bf16(ahi[ks], bl, facc[cb], 0, 0, 0);
        facc[cb] = __builtin_amdgcn_mfma_f32_16x16x32_bf16(alo[ks], bh, facc[cb], 0, 0, 0);
      }
    }
  }
  __syncthreads();                      // all tb reads done -> safe to alias
  if (wave == 1) {
#pragma unroll
    for (int cb = 0; cb < 4; ++cb)
#pragma unroll
      for (int q = 0; q < 4; ++q)
        xfer[(kg * 4 + q) * 65 + cb * 16 + idx15] = facc[cb][q];
  }
  __syncthreads();
  if (wave == 0) {
#pragma unroll
    for (int cb = 0; cb < 4; ++cb)
#pragma unroll
      for (int q = 0; q < 4; ++q) {
        int row = kg * 4 + q, col = cb * 16 + idx15;
        float v = facc[cb][q] + xfer[row * 65 + col];
        size_t o = ((size_t)task * 16 + row) * 64 + col;
        hn[o] = v;
        hnb[o] = bf16_rne(v);
      }
  }
}

// ====== fused pool+head: wave per graph, binary-search segment, no atomics ==
__global__ __launch_bounds__(64) void k_poolhead(
    const float* __restrict__ h, const int* __restrict__ batch,
    const float* __restrict__ l1W, const float* __restrict__ l1b,
    const float* __restrict__ l2W, const float* __restrict__ l2b,
    float* __restrict__ out)
{
  int g = blockIdx.x;
  int lane = threadIdx.x;
  // [start, end) = rows of graph g (batch sorted ascending)
  int lo = 0, hi = Nn;
  while (lo < hi) { int mid = (lo + hi) >> 1; if (batch[mid] < g) lo = mid + 1; else hi = mid; }
  int start = lo;
  hi = Nn;
  while (lo < hi) { int mid = (lo + hi) >> 1; if (batch[mid] < g + 1) lo = mid + 1; else hi = mid; }
  int end = lo;

  float acc = 0.0f;
  int i = start;
  for (; i + 3 < end; i += 4) {
    float v0 = h[(size_t)i * 64 + lane];
    float v1 = h[(size_t)(i + 1) * 64 + lane];
    float v2 = h[(size_t)(i + 2) * 64 + lane];
    float v3 = h[(size_t)(i + 3) * 64 + lane];
    acc += (v0 + v1) + (v2 + v3);
  }
  for (; i < end; ++i) acc += h[(size_t)i * 64 + lane];
  float p = acc / fmaxf((float)(end - start), 1.0f);

  float t = l1b[lane];
#pragma unroll
  for (int k = 0; k < Dd; ++k)
    t += __shfl(p, k, 64) * l1W[k * Dd + lane];
  t = fmaxf(t, 0.0f);
  float o = (lane < Cc) ? l2b[lane] : 0.0f;
#pragma unroll
  for (int k = 0; k < Dd; ++k) {
    float w = (lane < Cc) ? l2W[k * Cc + lane] : 0.0f;
    o += __shfl(t, k, 64) * w;
  }
  if (lane < Cc) out[(size_t)g * Cc + lane] = o;
}

extern "C" void kernel_launch(void* const* d_in, const int* in_sizes, int n_in,
                              void* d_out, int out_size, void* d_ws, size_t ws_size,
                              hipStream_t stream)
{
  const float* x     = (const float*)d_in[0];
  const int*   ei    = (const int*)d_in[1];
  const int*   et    = (const int*)d_in[2];
  const int*   batch = (const int*)d_in[3];
  const float* selfW = (const float*)d_in[4];
  const float* selfb = (const float*)d_in[5];
  const float* eps   = (const float*)d_in[6];
  const float* W1    = (const float*)d_in[7];
  const float* b1    = (const float*)d_in[8];
  const float* W2    = (const float*)d_in[9];
  const float* b2    = (const float*)d_in[10];
  const float* l1W   = (const float*)d_in[11];
  const float* l1b   = (const float*)d_in[12];
  const float* l2W   = (const float*)d_in[13];
  const float* l2b   = (const float*)d_in[14];
  float* out = (float*)d_out;

  // ws layout:
  // buf0[N*D]f buf1[N*D]f hb0[N*D]u16 hb1[N*D]u16
  // wtHi/wtLo[15*4096]u16 counts[NR] offs[NR+1] cursor[NR] btot[NB] bscan[NB]
  // elist[EPAD] (16B-aligned)
  float* buf0 = (float*)d_ws;
  float* buf1 = buf0 + (size_t)Nn * Dd;
  unsigned short* hb0 = (unsigned short*)(buf1 + (size_t)Nn * Dd);
  unsigned short* hb1 = hb0 + (size_t)Nn * Dd;
  unsigned short* wtHi = hb1 + (size_t)Nn * Dd;
  unsigned short* wtLo = wtHi + (size_t)Ll * 5 * 4096;
  int* counts = (int*)(wtLo + (size_t)Ll * 5 * 4096);
  int* offs   = counts + NR;
  int* cursor = offs + NR + 1;
  int* btot   = cursor + NR;
  int* bscan  = btot + NB;
  int* elist  = (int*)((((uintptr_t)(bscan + NB)) + 15) & ~(uintptr_t)15);

  const int* src = ei;
  const int* dst = ei + Ee;

  hipMemsetAsync(counts, 0, (size_t)NR * sizeof(int), stream);
  k_setup<<<CVT_B + PREP_B + HIST_B, 256, 0, stream>>>(
      x, hb0, selfW, W1, W2, wtHi, wtLo, dst, et, counts);

  // CSR build, padded segments (graph static across layers)
  k_scan1<<<NB, 1024, 0, stream>>>(counts, offs, btot);
  k_scan2<<<1, 128, 0, stream>>>(btot, bscan);
  k_scan3<<<NB, 1024, 0, stream>>>(counts, bscan, offs, cursor);
  k_fill<<<(Ee + 255) / 256, 256, 0, stream>>>(src, dst, et, cursor, elist);

  const float* h = x;
  const unsigned short* hbc = hb0;
  float* hn = buf0;
  unsigned short* hnb = hb1;
  for (int l = 0; l < Ll; ++l) {
    k_update<<<NT, 128, 0, stream>>>(h, hbc, offs, counts, elist, wtHi, wtLo,
                                     selfb, eps, b1, b2, hn, hnb, l);
    h = hn;
    hbc = hnb;
    hn = (hn == buf0) ? buf1 : buf0;
    hnb = (hnb == hb0) ? hb1 : hb0;
  }
  k_poolhead<<<Gg, 64, 0, stream>>>(h, batch, l1W, l1b, l2W, l2b, out);
}

// Round 13
// 291.907 us; speedup vs baseline: 1.5478x; 1.0156x over previous
//
#include <hip/hip_runtime.h>

#define Nn 50000
#define Dd 64
#define Ee 800000
#define Ll 3
#define Rr 2
#define Gg 128
#define Cc 10
#define NR (Nn * Rr)
#define NB ((NR + 1023) / 1024)
#define NT (Nn / 16)   // 3125 tasks
#define EPAD (Ee + 4 * NR + 64)   // padded elist capacity

// k_setup block ranges (all exact multiples of 256)
#define CVT_B  3125    // Nn*Dd/4 / 256
#define PREP_B 240     // 15*4096 / 256
#define HIST_B 3125    // Ee / 256

typedef __attribute__((ext_vector_type(8))) short short8;
typedef __attribute__((ext_vector_type(4))) float f32x4;

__device__ __forceinline__ unsigned short bf16_rne(float x) {
  unsigned u = __float_as_uint(x);
  unsigned r = u + 0x7fffu + ((u >> 16) & 1u);
  return (unsigned short)(r >> 16);
}
__device__ __forceinline__ float bf16_tof(unsigned short b) {
  return __uint_as_float(((unsigned)b) << 16);
}
// accumulate 8 bf16 (packed in uint4) into z[0..7], f32
__device__ __forceinline__ void acc8(float* z, uint4 u) {
  z[0] += __uint_as_float(u.x << 16);
  z[1] += __uint_as_float(u.x & 0xffff0000u);
  z[2] += __uint_as_float(u.y << 16);
  z[3] += __uint_as_float(u.y & 0xffff0000u);
  z[4] += __uint_as_float(u.z << 16);
  z[5] += __uint_as_float(u.z & 0xffff0000u);
  z[6] += __uint_as_float(u.w << 16);
  z[7] += __uint_as_float(u.w & 0xffff0000u);
}

// ========== fused setup: x->bf16 shadow | weight split-bf16 prep | hist =====
__global__ __launch_bounds__(256) void k_setup(
    const float* __restrict__ x, unsigned short* __restrict__ hb,
    const float* __restrict__ selfW, const float* __restrict__ W1,
    const float* __restrict__ W2, unsigned short* __restrict__ wtHi,
    unsigned short* __restrict__ wtLo,
    const int* __restrict__ dst, const int* __restrict__ et,
    int* __restrict__ counts)
{
  int b = blockIdx.x;
  if (b < CVT_B) {
    int i = b * 256 + threadIdx.x;            // < 800000 exactly
    const float4 v = *(const float4*)&x[(size_t)i * 4];
    ushort4 o;
    o.x = bf16_rne(v.x); o.y = bf16_rne(v.y);
    o.z = bf16_rne(v.z); o.w = bf16_rne(v.w);
    *(ushort4*)&hb[(size_t)i * 4] = o;
  } else if (b < CVT_B + PREP_B) {
    int i = (b - CVT_B) * 256 + threadIdx.x;  // < 61440 exactly
    int l = i / (5 * 4096);
    int rem = i - l * 5 * 4096;
    int m = rem >> 12;
    int e = rem & 4095;
    int k = e >> 6, c = e & 63;
    const float* p;
    if (m == 0)      p = selfW + (size_t)l * 4096;
    else if (m == 1) p = W1 + ((size_t)l * 2 + 0) * 4096;
    else if (m == 2) p = W2 + ((size_t)l * 2 + 0) * 4096;
    else if (m == 3) p = W1 + ((size_t)l * 2 + 1) * 4096;
    else             p = W2 + ((size_t)l * 2 + 1) * 4096;
    float w = p[e];
    unsigned short hi = bf16_rne(w);
    unsigned short lo = bf16_rne(w - bf16_tof(hi));
    size_t o = ((size_t)(l * 5 + m) * 64 + c) * 64 + k;
    wtHi[o] = hi;
    wtLo[o] = lo;
  } else {
    int e = (b - CVT_B - PREP_B) * 256 + threadIdx.x;  // < Ee exactly
    atomicAdd(&counts[et[e] * Nn + dst[e]], 1);
  }
}

// ================= CSR scan + fill (segments padded to 4-int multiples) =====
__global__ __launch_bounds__(1024) void k_scan1(
    const int* __restrict__ counts, int* __restrict__ offs,
    int* __restrict__ btot)
{
  __shared__ int s[1024];
  int i = blockIdx.x * 1024 + threadIdx.x;
  int v = (i < NR) ? ((counts[i] + 3) & ~3) : 0;   // padded count
  s[threadIdx.x] = v;
  __syncthreads();
#pragma unroll
  for (int d = 1; d < 1024; d <<= 1) {
    int t = (threadIdx.x >= d) ? s[threadIdx.x - d] : 0;
    __syncthreads();
    s[threadIdx.x] += t;
    __syncthreads();
  }
  if (i < NR) offs[i + 1] = s[threadIdx.x];
  if (threadIdx.x == 1023) btot[blockIdx.x] = s[1023];
}

// scan2 merged into scan3: every block re-derives the 98-entry block prefix
__global__ __launch_bounds__(1024) void k_scan3(
    const int* __restrict__ counts, const int* __restrict__ btot,
    int* __restrict__ offs, int* __restrict__ cursor)
{
  __shared__ int bs[128];
  int v = (threadIdx.x < NB) ? btot[threadIdx.x] : 0;
  if (threadIdx.x < 128) bs[threadIdx.x] = v;
  __syncthreads();
#pragma unroll
  for (int d = 1; d < 128; d <<= 1) {
    int t = (threadIdx.x >= d && threadIdx.x < 128) ? bs[threadIdx.x - d] : 0;
    __syncthreads();
    if (threadIdx.x < 128) bs[threadIdx.x] += t;
    __syncthreads();
  }
  int myb = (blockIdx.x == 0) ? 0 : bs[blockIdx.x - 1];  // exclusive prefix
  int i = blockIdx.x * 1024 + threadIdx.x;
  if (i >= NR) return;
  int o = offs[i + 1] + myb;
  offs[i + 1] = o;
  cursor[i] = o - ((counts[i] + 3) & ~3);   // 16B-aligned segment start
  if (i == 0) offs[0] = 0;
}

__global__ __launch_bounds__(256) void k_fill(
    const int* __restrict__ src, const int* __restrict__ dst,
    const int* __restrict__ et, int* __restrict__ cursor,
    int* __restrict__ elist)
{
  int e = blockIdx.x * 256 + threadIdx.x;
  if (e >= Ee) return;
  int pos = atomicAdd(&cursor[et[e] * Nn + dst[e]], 1);
  elist[pos] = src[e];
}

// ====== fused per-layer update: (task, relation) per wave + LDS combine =====
// Gather: 8-edge unroll -> 16 row-half uint4 loads in flight per wave,
// double-int4 elist prefetch so addresses never wait on the index load.
#define WOFF(m, c, ks) ((size_t)(m)*4096 + (size_t)(c)*64 + (ks)*32 + koff)

__global__ __launch_bounds__(128, 4) void k_update(
    const float* __restrict__ h, const unsigned short* __restrict__ hb,
    const int* __restrict__ offs, const int* __restrict__ counts,
    const int* __restrict__ elist,
    const unsigned short* __restrict__ wtHi, const unsigned short* __restrict__ wtLo,
    const float* __restrict__ selfb, const float* __restrict__ eps,
    const float* __restrict__ b1, const float* __restrict__ b2,
    float* __restrict__ hn, unsigned short* __restrict__ hnb, int l)
{
  __shared__ __align__(16) unsigned short tbh[2][16 * 72];  // 4608 B
  __shared__ __align__(16) unsigned short tbl[2][16 * 72];  // 4608 B
  float* xfer = (float*)&tbh[0][0];     // aliased: tb dead by combine time
  const int wave = threadIdx.x >> 6;    // = relation r
  const int lane = threadIdx.x & 63;
  const int task = blockIdx.x;
  const int r = wave;
  const int idx15 = lane & 15;
  const int kg = lane >> 4;
  const int koff = kg * 8;
  const int nodeA = task * 16 + idx15;

  // h row fragment (row = idx15, features koff..koff+7 per kstep), f32
  float f[2][8];
  {
    const float* hp = &h[(size_t)nodeA * 64 + koff];
    const float4 a0 = *(const float4*)(hp);
    const float4 a1 = *(const float4*)(hp + 4);
    const float4 b0 = *(const float4*)(hp + 32);
    const float4 b1v = *(const float4*)(hp + 36);
    f[0][0] = a0.x; f[0][1] = a0.y; f[0][2] = a0.z; f[0][3] = a0.w;
    f[0][4] = a1.x; f[0][5] = a1.y; f[0][6] = a1.z; f[0][7] = a1.w;
    f[1][0] = b0.x; f[1][1] = b0.y; f[1][2] = b0.z; f[1][3] = b0.w;
    f[1][4] = b1v.x; f[1][5] = b1v.y; f[1][6] = b1v.z; f[1][7] = b1v.w;
  }

  const unsigned short* whi = wtHi + (size_t)l * 5 * 4096;
  const unsigned short* wlo = wtLo + (size_t)l * 5 * 4096;
  const int m1 = 1 + 2 * r, m2 = 2 + 2 * r;
  const float er = 1.0f + eps[l * Rr + r];

  // ---- CSR gather: 8 edges (16 uint4 row-halves) in flight ------------------
  float za[2][8];
#pragma unroll
  for (int ks = 0; ks < 2; ++ks)
#pragma unroll
    for (int jj = 0; jj < 8; ++jj) za[ks][jj] = 0.0f;
  {
    const int aidx = r * Nn + nodeA;
    const int jb = offs[aidx];            // 16B-aligned
    const int je = jb + counts[aidx];
    int j = jb;
    if (j + 7 < je) {
      int4 ec0 = *(const int4*)&elist[j];
      int4 ec1 = *(const int4*)&elist[j + 4];
      for (; j + 7 < je; j += 8) {
        int4 en0 = *(const int4*)&elist[j + 8];    // prefetch (padded: safe)
        int4 en1 = *(const int4*)&elist[j + 12];
        const unsigned short* q0 = &hb[(size_t)ec0.x * 64 + koff];
        const unsigned short* q1 = &hb[(size_t)ec0.y * 64 + koff];
        const unsigned short* q2 = &hb[(size_t)ec0.z * 64 + koff];
        const unsigned short* q3 = &hb[(size_t)ec0.w * 64 + koff];
        const unsigned short* q4 = &hb[(size_t)ec1.x * 64 + koff];
        const unsigned short* q5 = &hb[(size_t)ec1.y * 64 + koff];
        const unsigned short* q6 = &hb[(size_t)ec1.z * 64 + koff];
        const unsigned short* q7 = &hb[(size_t)ec1.w * 64 + koff];
        const uint4 a0 = *(const uint4*)(q0);
        const uint4 a1 = *(const uint4*)(q1);
        const uint4 a2 = *(const uint4*)(q2);
        const uint4 a3 = *(const uint4*)(q3);
        const uint4 a4 = *(const uint4*)(q4);
        const uint4 a5 = *(const uint4*)(q5);
        const uint4 a6 = *(const uint4*)(q6);
        const uint4 a7 = *(const uint4*)(q7);
        const uint4 b0 = *(const uint4*)(q0 + 32);
        const uint4 b1q = *(const uint4*)(q1 + 32);
        const uint4 b2q = *(const uint4*)(q2 + 32);
        const uint4 b3 = *(const uint4*)(q3 + 32);
        const uint4 b4 = *(const uint4*)(q4 + 32);
        const uint4 b5 = *(const uint4*)(q5 + 32);
        const uint4 b6 = *(const uint4*)(q6 + 32);
        const uint4 b7 = *(const uint4*)(q7 + 32);
        acc8(za[0], a0); acc8(za[0], a1); acc8(za[0], a2); acc8(za[0], a3);
        acc8(za[0], a4); acc8(za[0], a5); acc8(za[0], a6); acc8(za[0], a7);
        acc8(za[1], b0); acc8(za[1], b1q); acc8(za[1], b2q); acc8(za[1], b3);
        acc8(za[1], b4); acc8(za[1], b5); acc8(za[1], b6); acc8(za[1], b7);
        ec0 = en0; ec1 = en1;
      }
    }
    if (j + 3 < je) {
      int4 ec = *(const int4*)&elist[j];
      const unsigned short* q0 = &hb[(size_t)ec.x * 64 + koff];
      const unsigned short* q1 = &hb[(size_t)ec.y * 64 + koff];
      const unsigned short* q2 = &hb[(size_t)ec.z * 64 + koff];
      const unsigned short* q3 = &hb[(size_t)ec.w * 64 + koff];
      const uint4 a0 = *(const uint4*)(q0);
      const uint4 a1 = *(const uint4*)(q1);
      const uint4 a2 = *(const uint4*)(q2);
      const uint4 a3 = *(const uint4*)(q3);
      const uint4 b0 = *(const uint4*)(q0 + 32);
      const uint4 b1q = *(const uint4*)(q1 + 32);
      const uint4 b2q = *(const uint4*)(q2 + 32);
      const uint4 b3 = *(const uint4*)(q3 + 32);
      acc8(za[0], a0); acc8(za[0], a1); acc8(za[0], a2); acc8(za[0], a3);
      acc8(za[1], b0); acc8(za[1], b1q); acc8(za[1], b2q); acc8(za[1], b3);
      j += 4;
    }
    for (; j < je; ++j) {
      const unsigned short* q = &hb[(size_t)elist[j] * 64 + koff];
      const uint4 a = *(const uint4*)(q);
      const uint4 b = *(const uint4*)(q + 32);
      acc8(za[0], a); acc8(za[1], b);
    }
  }

  // z = er*h + za -> split bf16
  short8 zhi[2], zlo[2];
#pragma unroll
  for (int ks = 0; ks < 2; ++ks)
#pragma unroll
    for (int jj = 0; jj < 8; ++jj) {
      float zf = er * f[ks][jj] + za[ks][jj];
      unsigned short hb2 = bf16_rne(zf);
      zhi[ks][jj] = (short)hb2;
      zlo[ks][jj] = (short)bf16_rne(zf - bf16_tof(hb2));
    }

  // MLP1: tacc = relu(z @ W1_r + b1_r)
  f32x4 tacc[4];
#pragma unroll
  for (int cb = 0; cb < 4; ++cb) {
    float bi = b1[((size_t)l * 2 + r) * 64 + cb * 16 + idx15];
    tacc[cb] = (f32x4){bi, bi, bi, bi};
  }
#pragma unroll
  for (int cb = 0; cb < 4; ++cb) {
    int c = cb * 16 + idx15;
#pragma unroll
    for (int ks = 0; ks < 2; ++ks) {
      const short8 bh = *(const short8*)&whi[WOFF(m1, c, ks)];
      const short8 bl = *(const short8*)&wlo[WOFF(m1, c, ks)];
      tacc[cb] = __builtin_amdgcn_mfma_f32_16x16x32_bf16(zhi[ks], bh, tacc[cb], 0, 0, 0);
      tacc[cb] = __builtin_amdgcn_mfma_f32_16x16x32_bf16(zhi[ks], bl, tacc[cb], 0, 0, 0);
      tacc[cb] = __builtin_amdgcn_mfma_f32_16x16x32_bf16(zlo[ks], bh, tacc[cb], 0, 0, 0);
    }
  }
  // relu -> split-bf16 -> LDS transpose bounce (per-wave buffer, no barrier)
#pragma unroll
  for (int cb = 0; cb < 4; ++cb)
#pragma unroll
    for (int q = 0; q < 4; ++q) {
      float tv = fmaxf(tacc[cb][q], 0.0f);
      unsigned short hb2 = bf16_rne(tv);
      tbh[wave][(kg * 4 + q) * 72 + cb * 16 + idx15] = hb2;
      tbl[wave][(kg * 4 + q) * 72 + cb * 16 + idx15] = bf16_rne(tv - bf16_tof(hb2));
    }
  asm volatile("s_waitcnt lgkmcnt(0)" ::: "memory");
  __builtin_amdgcn_sched_barrier(0);
  short8 thi[2], tlo[2];
#pragma unroll
  for (int ks = 0; ks < 2; ++ks) {
    thi[ks] = *(const short8*)&tbh[wave][idx15 * 72 + ks * 32 + koff];
    tlo[ks] = *(const short8*)&tbl[wave][idx15 * 72 + ks * 32 + koff];
  }

  // MLP2 (+ wave1: self GEMM); facc = partial output
  f32x4 facc[4];
#pragma unroll
  for (int cb = 0; cb < 4; ++cb) {
    int c = cb * 16 + idx15;
    float bi = b2[((size_t)l * 2 + r) * 64 + c];
    if (wave == 1) bi += selfb[l * 64 + c];
    facc[cb] = (f32x4){bi, bi, bi, bi};
  }
#pragma unroll
  for (int cb = 0; cb < 4; ++cb) {
    int c = cb * 16 + idx15;
#pragma unroll
    for (int ks = 0; ks < 2; ++ks) {
      const short8 bh = *(const short8*)&whi[WOFF(m2, c, ks)];
      const short8 bl = *(const short8*)&wlo[WOFF(m2, c, ks)];
      facc[cb] = __builtin_amdgcn_mfma_f32_16x16x32_bf16(thi[ks], bh, facc[cb], 0, 0, 0);
      facc[cb] = __builtin_amdgcn_mfma_f32_16x16x32_bf16(thi[ks], bl, facc[cb], 0, 0, 0);
      facc[cb] = __builtin_amdgcn_mfma_f32_16x16x32_bf16(tlo[ks], bh, facc[cb], 0, 0, 0);
    }
  }
  if (wave == 1) {
    short8 ahi[2], alo[2];
#pragma unroll
    for (int ks = 0; ks < 2; ++ks)
#pragma unroll
      for (int jj = 0; jj < 8; ++jj) {
        unsigned short hb2 = bf16_rne(f[ks][jj]);
        ahi[ks][jj] = (short)hb2;
        alo[ks][jj] = (short)bf16_rne(f[ks][jj] - bf16_tof(hb2));
      }
#pragma unroll
    for (int cb = 0; cb < 4; ++cb) {
      int c = cb * 16 + idx15;
#pragma unroll
      for (int ks = 0; ks < 2; ++ks) {
        const short8 bh = *(const short8*)&whi[WOFF(0, c, ks)];
        const short8 bl = *(const short8*)&wlo[WOFF(0, c, ks)];
        facc[cb] = __builtin_amdgcn_mfma_f32_16x16x32_bf16(ahi[ks], bh, facc[cb], 0, 0, 0);
        facc[cb] = __builtin_amdgcn_mfma_f32_16x16x32_bf16(ahi[ks], bl, facc[cb], 0, 0, 0);
        facc[cb] = __builtin_amdgcn_mfma_f32_16x16x32_bf16(alo[ks], bh, facc[cb], 0, 0, 0);
      }
    }
  }
  __syncthreads();                      // all tb reads done -> safe to alias
  if (wave == 1) {
#pragma unroll
    for (int cb = 0; cb < 4; ++cb)
#pragma unroll
      for (int q = 0; q < 4; ++q)
        xfer[(kg * 4 + q) * 65 + cb * 16 + idx15] = facc[cb][q];
  }
  __syncthreads();
  if (wave == 0) {
#pragma unroll
    for (int cb = 0; cb < 4; ++cb)
#pragma unroll
      for (int q = 0; q < 4; ++q) {
        int row = kg * 4 + q, col = cb * 16 + idx15;
        float v = facc[cb][q] + xfer[row * 65 + col];
        size_t o = ((size_t)task * 16 + row) * 64 + col;
        hn[o] = v;
        hnb[o] = bf16_rne(v);
      }
  }
}

// ====== fused pool+head: wave per graph, binary-search segment, no atomics ==
__global__ __launch_bounds__(64) void k_poolhead(
    const float* __restrict__ h, const int* __restrict__ batch,
    const float* __restrict__ l1W, const float* __restrict__ l1b,
    const float* __restrict__ l2W, const float* __restrict__ l2b,
    float* __restrict__ out)
{
  int g = blockIdx.x;
  int lane = threadIdx.x;
  // [start, end) = rows of graph g (batch sorted ascending)
  int lo = 0, hi = Nn;
  while (lo < hi) { int mid = (lo + hi) >> 1; if (batch[mid] < g) lo = mid + 1; else hi = mid; }
  int start = lo;
  hi = Nn;
  while (lo < hi) { int mid = (lo + hi) >> 1; if (batch[mid] < g + 1) lo = mid + 1; else hi = mid; }
  int end = lo;

  float acc = 0.0f;
  int i = start;
  for (; i + 3 < end; i += 4) {
    float v0 = h[(size_t)i * 64 + lane];
    float v1 = h[(size_t)(i + 1) * 64 + lane];
    float v2 = h[(size_t)(i + 2) * 64 + lane];
    float v3 = h[(size_t)(i + 3) * 64 + lane];
    acc += (v0 + v1) + (v2 + v3);
  }
  for (; i < end; ++i) acc += h[(size_t)i * 64 + lane];
  float p = acc / fmaxf((float)(end - start), 1.0f);

  float t = l1b[lane];
#pragma unroll
  for (int k = 0; k < Dd; ++k)
    t += __shfl(p, k, 64) * l1W[k * Dd + lane];
  t = fmaxf(t, 0.0f);
  float o = (lane < Cc) ? l2b[lane] : 0.0f;
#pragma unroll
  for (int k = 0; k < Dd; ++k) {
    float w = (lane < Cc) ? l2W[k * Cc + lane] : 0.0f;
    o += __shfl(t, k, 64) * w;
  }
  if (lane < Cc) out[(size_t)g * Cc + lane] = o;
}

extern "C" void kernel_launch(void* const* d_in, const int* in_sizes, int n_in,
                              void* d_out, int out_size, void* d_ws, size_t ws_size,
                              hipStream_t stream)
{
  const float* x     = (const float*)d_in[0];
  const int*   ei    = (const int*)d_in[1];
  const int*   et    = (const int*)d_in[2];
  const int*   batch = (const int*)d_in[3];
  const float* selfW = (const float*)d_in[4];
  const float* selfb = (const float*)d_in[5];
  const float* eps   = (const float*)d_in[6];
  const float* W1    = (const float*)d_in[7];
  const float* b1    = (const float*)d_in[8];
  const float* W2    = (const float*)d_in[9];
  const float* b2    = (const float*)d_in[10];
  const float* l1W   = (const float*)d_in[11];
  const float* l1b   = (const float*)d_in[12];
  const float* l2W   = (const float*)d_in[13];
  const float* l2b   = (const float*)d_in[14];
  float* out = (float*)d_out;

  // ws layout:
  // buf0[N*D]f buf1[N*D]f hb0[N*D]u16 hb1[N*D]u16
  // wtHi/wtLo[15*4096]u16 counts[NR] offs[NR+1] cursor[NR] btot[NB]
  // elist[EPAD] (16B-aligned)
  float* buf0 = (float*)d_ws;
  float* buf1 = buf0 + (size_t)Nn * Dd;
  unsigned short* hb0 = (unsigned short*)(buf1 + (size_t)Nn * Dd);
  unsigned short* hb1 = hb0 + (size_t)Nn * Dd;
  unsigned short* wtHi = hb1 + (size_t)Nn * Dd;
  unsigned short* wtLo = wtHi + (size_t)Ll * 5 * 4096;
  int* counts = (int*)(wtLo + (size_t)Ll * 5 * 4096);
  int* offs   = counts + NR;
  int* cursor = offs + NR + 1;
  int* btot   = cursor + NR;
  int* elist  = (int*)((((uintptr_t)(btot + NB)) + 15) & ~(uintptr_t)15);

  const int* src = ei;
  const int* dst = ei + Ee;

  hipMemsetAsync(counts, 0, (size_t)NR * sizeof(int), stream);
  k_setup<<<CVT_B + PREP_B + HIST_B, 256, 0, stream>>>(
      x, hb0, selfW, W1, W2, wtHi, wtLo, dst, et, counts);

  // CSR build, padded segments (graph static across layers)
  k_scan1<<<NB, 1024, 0, stream>>>(counts, offs, btot);
  k_scan3<<<NB, 1024, 0, stream>>>(counts, btot, offs, cursor);
  k_fill<<<(Ee + 255) / 256, 256, 0, stream>>>(src, dst, et, cursor, elist);

  const float* h = x;
  const unsigned short* hbc = hb0;
  float* hn = buf0;
  unsigned short* hnb = hb1;
  for (int l = 0; l < Ll; ++l) {
    k_update<<<NT, 128, 0, stream>>>(h, hbc, offs, counts, elist, wtHi, wtLo,
                                     selfb, eps, b1, b2, hn, hnb, l);
    h = hn;
    hbc = hnb;
    hn = (hn == buf0) ? buf1 : buf0;
    hnb = (hnb == hb0) ? hb1 : hb0;
  }
  k_poolhead<<<Gg, 64, 0, stream>>>(h, batch, l1W, l1b, l2W, l2b, out);
}

// Round 14
// 272.231 us; speedup vs baseline: 1.6597x; 1.0723x over previous
//
#include <hip/hip_runtime.h>

#define Nn 50000
#define Dd 64
#define Ee 800000
#define Ll 3
#define Rr 2
#define Gg 128
#define Cc 10
#define NR (Nn * Rr)
#define NB ((NR + 1023) / 1024)
#define NT (Nn / 16)   // 3125 tasks

// k_setup block ranges (all exact multiples of 256)
#define CVT_B  3125    // Nn*Dd/4 / 256
#define PREP_B 240     // 15*4096 / 256
#define HIST_B 3125    // Ee / 256

typedef __attribute__((ext_vector_type(8))) short short8;
typedef __attribute__((ext_vector_type(4))) float f32x4;

__device__ __forceinline__ unsigned short bf16_rne(float x) {
  unsigned u = __float_as_uint(x);
  unsigned r = u + 0x7fffu + ((u >> 16) & 1u);
  return (unsigned short)(r >> 16);
}
__device__ __forceinline__ float bf16_tof(unsigned short b) {
  return __uint_as_float(((unsigned)b) << 16);
}
// accumulate 8 bf16 (packed in uint4) into z[0..7], f32
__device__ __forceinline__ void acc8(float* z, uint4 u) {
  z[0] += __uint_as_float(u.x << 16);
  z[1] += __uint_as_float(u.x & 0xffff0000u);
  z[2] += __uint_as_float(u.y << 16);
  z[3] += __uint_as_float(u.y & 0xffff0000u);
  z[4] += __uint_as_float(u.z << 16);
  z[5] += __uint_as_float(u.z & 0xffff0000u);
  z[6] += __uint_as_float(u.w << 16);
  z[7] += __uint_as_float(u.w & 0xffff0000u);
}

// ========== fused setup: x->bf16 shadow | weight split-bf16 prep | hist =====
__global__ __launch_bounds__(256) void k_setup(
    const float* __restrict__ x, unsigned short* __restrict__ hb,
    const float* __restrict__ selfW, const float* __restrict__ W1,
    const float* __restrict__ W2, unsigned short* __restrict__ wtHi,
    unsigned short* __restrict__ wtLo,
    const int* __restrict__ dst, const int* __restrict__ et,
    int* __restrict__ counts)
{
  int b = blockIdx.x;
  if (b < CVT_B) {
    int i = b * 256 + threadIdx.x;            // < 800000 exactly
    const float4 v = *(const float4*)&x[(size_t)i * 4];
    ushort4 o;
    o.x = bf16_rne(v.x); o.y = bf16_rne(v.y);
    o.z = bf16_rne(v.z); o.w = bf16_rne(v.w);
    *(ushort4*)&hb[(size_t)i * 4] = o;
  } else if (b < CVT_B + PREP_B) {
    int i = (b - CVT_B) * 256 + threadIdx.x;  // < 61440 exactly
    int l = i / (5 * 4096);
    int rem = i - l * 5 * 4096;
    int m = rem >> 12;
    int e = rem & 4095;
    int k = e >> 6, c = e & 63;
    const float* p;
    if (m == 0)      p = selfW + (size_t)l * 4096;
    else if (m == 1) p = W1 + ((size_t)l * 2 + 0) * 4096;
    else if (m == 2) p = W2 + ((size_t)l * 2 + 0) * 4096;
    else if (m == 3) p = W1 + ((size_t)l * 2 + 1) * 4096;
    else             p = W2 + ((size_t)l * 2 + 1) * 4096;
    float w = p[e];
    unsigned short hi = bf16_rne(w);
    unsigned short lo = bf16_rne(w - bf16_tof(hi));
    size_t o = ((size_t)(l * 5 + m) * 64 + c) * 64 + k;
    wtHi[o] = hi;
    wtLo[o] = lo;
  } else {
    int e = (b - CVT_B - PREP_B) * 256 + threadIdx.x;  // < Ee exactly
    atomicAdd(&counts[et[e] * Nn + dst[e]], 1);
  }
}

// ================= CSR scan + fill (segments padded to 4-int multiples) =====
__global__ __launch_bounds__(1024) void k_scan1(
    const int* __restrict__ counts, int* __restrict__ offs,
    int* __restrict__ btot)
{
  __shared__ int s[1024];
  int i = blockIdx.x * 1024 + threadIdx.x;
  int v = (i < NR) ? ((counts[i] + 3) & ~3) : 0;   // padded count
  s[threadIdx.x] = v;
  __syncthreads();
#pragma unroll
  for (int d = 1; d < 1024; d <<= 1) {
    int t = (threadIdx.x >= d) ? s[threadIdx.x - d] : 0;
    __syncthreads();
    s[threadIdx.x] += t;
    __syncthreads();
  }
  if (i < NR) offs[i + 1] = s[threadIdx.x];
  if (threadIdx.x == 1023) btot[blockIdx.x] = s[1023];
}

// scan2 merged into scan3: every block re-derives the 98-entry block prefix
__global__ __launch_bounds__(1024) void k_scan3(
    const int* __restrict__ counts, const int* __restrict__ btot,
    int* __restrict__ offs, int* __restrict__ cursor)
{
  __shared__ int bs[128];
  int v = (threadIdx.x < NB) ? btot[threadIdx.x] : 0;
  if (threadIdx.x < 128) bs[threadIdx.x] = v;
  __syncthreads();
#pragma unroll
  for (int d = 1; d < 128; d <<= 1) {
    int t = (threadIdx.x >= d && threadIdx.x < 128) ? bs[threadIdx.x - d] : 0;
    __syncthreads();
    if (threadIdx.x < 128) bs[threadIdx.x] += t;
    __syncthreads();
  }
  int myb = (blockIdx.x == 0) ? 0 : bs[blockIdx.x - 1];  // exclusive prefix
  int i = blockIdx.x * 1024 + threadIdx.x;
  if (i >= NR) return;
  int o = offs[i + 1] + myb;
  offs[i + 1] = o;
  cursor[i] = o - ((counts[i] + 3) & ~3);   // 16B-aligned segment start
  if (i == 0) offs[0] = 0;
}

__global__ __launch_bounds__(256) void k_fill(
    const int* __restrict__ src, const int* __restrict__ dst,
    const int* __restrict__ et, int* __restrict__ cursor,
    int* __restrict__ elist)
{
  int e = blockIdx.x * 256 + threadIdx.x;
  if (e >= Ee) return;
  int pos = atomicAdd(&cursor[et[e] * Nn + dst[e]], 1);
  elist[pos] = src[e];
}

// ====== fused per-layer update: (task, relation) per wave + LDS combine =====
// h lives ONLY as bf16 (hb). Gather: 8-edge unroll, double-int4 elist prefetch.
#define WOFF(m, c, ks) ((size_t)(m)*4096 + (size_t)(c)*64 + (ks)*32 + koff)

__global__ __launch_bounds__(128, 4) void k_update(
    const unsigned short* __restrict__ hb,
    const int* __restrict__ offs, const int* __restrict__ counts,
    const int* __restrict__ elist,
    const unsigned short* __restrict__ wtHi, const unsigned short* __restrict__ wtLo,
    const float* __restrict__ selfb, const float* __restrict__ eps,
    const float* __restrict__ b1, const float* __restrict__ b2,
    unsigned short* __restrict__ hnb, int l)
{
  __shared__ __align__(16) unsigned short tbh[2][16 * 72];  // 4608 B
  __shared__ __align__(16) unsigned short tbl[2][16 * 72];  // 4608 B
  float* xfer = (float*)&tbh[0][0];     // aliased: tb dead by combine time
  const int wave = threadIdx.x >> 6;    // = relation r
  const int lane = threadIdx.x & 63;
  const int task = blockIdx.x;
  const int r = wave;
  const int idx15 = lane & 15;
  const int kg = lane >> 4;
  const int koff = kg * 8;
  const int nodeA = task * 16 + idx15;

  // own row (bf16-exact), features koff..koff+7 per kstep
  uint4 u0, u1;
  {
    const unsigned short* hp = &hb[(size_t)nodeA * 64 + koff];
    u0 = *(const uint4*)(hp);
    u1 = *(const uint4*)(hp + 32);
  }
  float f[2][8];
  f[0][0] = __uint_as_float(u0.x << 16); f[0][1] = __uint_as_float(u0.x & 0xffff0000u);
  f[0][2] = __uint_as_float(u0.y << 16); f[0][3] = __uint_as_float(u0.y & 0xffff0000u);
  f[0][4] = __uint_as_float(u0.z << 16); f[0][5] = __uint_as_float(u0.z & 0xffff0000u);
  f[0][6] = __uint_as_float(u0.w << 16); f[0][7] = __uint_as_float(u0.w & 0xffff0000u);
  f[1][0] = __uint_as_float(u1.x << 16); f[1][1] = __uint_as_float(u1.x & 0xffff0000u);
  f[1][2] = __uint_as_float(u1.y << 16); f[1][3] = __uint_as_float(u1.y & 0xffff0000u);
  f[1][4] = __uint_as_float(u1.z << 16); f[1][5] = __uint_as_float(u1.z & 0xffff0000u);
  f[1][6] = __uint_as_float(u1.w << 16); f[1][7] = __uint_as_float(u1.w & 0xffff0000u);

  const unsigned short* whi = wtHi + (size_t)l * 5 * 4096;
  const unsigned short* wlo = wtLo + (size_t)l * 5 * 4096;
  const int m1 = 1 + 2 * r, m2 = 2 + 2 * r;
  const float er = 1.0f + eps[l * Rr + r];

  // ---- CSR gather: 8 edges (16 uint4 row-halves) in flight ------------------
  float za[2][8];
#pragma unroll
  for (int ks = 0; ks < 2; ++ks)
#pragma unroll
    for (int jj = 0; jj < 8; ++jj) za[ks][jj] = 0.0f;
  {
    const int aidx = r * Nn + nodeA;
    const int jb = offs[aidx];            // 16B-aligned
    const int je = jb + counts[aidx];
    int j = jb;
    if (j + 7 < je) {
      int4 ec0 = *(const int4*)&elist[j];
      int4 ec1 = *(const int4*)&elist[j + 4];
      for (; j + 7 < je; j += 8) {
        int4 en0 = *(const int4*)&elist[j + 8];    // prefetch (padded: safe)
        int4 en1 = *(const int4*)&elist[j + 12];
        const unsigned short* q0 = &hb[(size_t)ec0.x * 64 + koff];
        const unsigned short* q1 = &hb[(size_t)ec0.y * 64 + koff];
        const unsigned short* q2 = &hb[(size_t)ec0.z * 64 + koff];
        const unsigned short* q3 = &hb[(size_t)ec0.w * 64 + koff];
        const unsigned short* q4 = &hb[(size_t)ec1.x * 64 + koff];
        const unsigned short* q5 = &hb[(size_t)ec1.y * 64 + koff];
        const unsigned short* q6 = &hb[(size_t)ec1.z * 64 + koff];
        const unsigned short* q7 = &hb[(size_t)ec1.w * 64 + koff];
        const uint4 a0 = *(const uint4*)(q0);
        const uint4 a1 = *(const uint4*)(q1);
        const uint4 a2 = *(const uint4*)(q2);
        const uint4 a3 = *(const uint4*)(q3);
        const uint4 a4 = *(const uint4*)(q4);
        const uint4 a5 = *(const uint4*)(q5);
        const uint4 a6 = *(const uint4*)(q6);
        const uint4 a7 = *(const uint4*)(q7);
        const uint4 b0 = *(const uint4*)(q0 + 32);
        const uint4 b1q = *(const uint4*)(q1 + 32);
        const uint4 b2q = *(const uint4*)(q2 + 32);
        const uint4 b3 = *(const uint4*)(q3 + 32);
        const uint4 b4 = *(const uint4*)(q4 + 32);
        const uint4 b5 = *(const uint4*)(q5 + 32);
        const uint4 b6 = *(const uint4*)(q6 + 32);
        const uint4 b7 = *(const uint4*)(q7 + 32);
        acc8(za[0], a0); acc8(za[0], a1); acc8(za[0], a2); acc8(za[0], a3);
        acc8(za[0], a4); acc8(za[0], a5); acc8(za[0], a6); acc8(za[0], a7);
        acc8(za[1], b0); acc8(za[1], b1q); acc8(za[1], b2q); acc8(za[1], b3);
        acc8(za[1], b4); acc8(za[1], b5); acc8(za[1], b6); acc8(za[1], b7);
        ec0 = en0; ec1 = en1;
      }
    }
    if (j + 3 < je) {
      int4 ec = *(const int4*)&elist[j];
      const unsigned short* q0 = &hb[(size_t)ec.x * 64 + koff];
      const unsigned short* q1 = &hb[(size_t)ec.y * 64 + koff];
      const unsigned short* q2 = &hb[(size_t)ec.z * 64 + koff];
      const unsigned short* q3 = &hb[(size_t)ec.w * 64 + koff];
      const uint4 a0 = *(const uint4*)(q0);
      const uint4 a1 = *(const uint4*)(q1);
      const uint4 a2 = *(const uint4*)(q2);
      const uint4 a3 = *(const uint4*)(q3);
      const uint4 b0 = *(const uint4*)(q0 + 32);
      const uint4 b1q = *(const uint4*)(q1 + 32);
      const uint4 b2q = *(const uint4*)(q2 + 32);
      const uint4 b3 = *(const uint4*)(q3 + 32);
      acc8(za[0], a0); acc8(za[0], a1); acc8(za[0], a2); acc8(za[0], a3);
      acc8(za[1], b0); acc8(za[1], b1q); acc8(za[1], b2q); acc8(za[1], b3);
      j += 4;
    }
    for (; j < je; ++j) {
      const unsigned short* q = &hb[(size_t)elist[j] * 64 + koff];
      const uint4 a = *(const uint4*)(q);
      const uint4 b = *(const uint4*)(q + 32);
      acc8(za[0], a); acc8(za[1], b);
    }
  }

  // z = er*h + za -> split bf16
  short8 zhi[2], zlo[2];
#pragma unroll
  for (int ks = 0; ks < 2; ++ks)
#pragma unroll
    for (int jj = 0; jj < 8; ++jj) {
      float zf = er * f[ks][jj] + za[ks][jj];
      unsigned short hb2 = bf16_rne(zf);
      zhi[ks][jj] = (short)hb2;
      zlo[ks][jj] = (short)bf16_rne(zf - bf16_tof(hb2));
    }

  // MLP1: tacc = relu(z @ W1_r + b1_r)
  f32x4 tacc[4];
#pragma unroll
  for (int cb = 0; cb < 4; ++cb) {
    float bi = b1[((size_t)l * 2 + r) * 64 + cb * 16 + idx15];
    tacc[cb] = (f32x4){bi, bi, bi, bi};
  }
#pragma unroll
  for (int cb = 0; cb < 4; ++cb) {
    int c = cb * 16 + idx15;
#pragma unroll
    for (int ks = 0; ks < 2; ++ks) {
      const short8 bh = *(const short8*)&whi[WOFF(m1, c, ks)];
      const short8 bl = *(const short8*)&wlo[WOFF(m1, c, ks)];
      tacc[cb] = __builtin_amdgcn_mfma_f32_16x16x32_bf16(zhi[ks], bh, tacc[cb], 0, 0, 0);
      tacc[cb] = __builtin_amdgcn_mfma_f32_16x16x32_bf16(zhi[ks], bl, tacc[cb], 0, 0, 0);
      tacc[cb] = __builtin_amdgcn_mfma_f32_16x16x32_bf16(zlo[ks], bh, tacc[cb], 0, 0, 0);
    }
  }
  // relu -> split-bf16 -> LDS transpose bounce (per-wave buffer, no barrier)
#pragma unroll
  for (int cb = 0; cb < 4; ++cb)
#pragma unroll
    for (int q = 0; q < 4; ++q) {
      float tv = fmaxf(tacc[cb][q], 0.0f);
      unsigned short hb2 = bf16_rne(tv);
      tbh[wave][(kg * 4 + q) * 72 + cb * 16 + idx15] = hb2;
      tbl[wave][(kg * 4 + q) * 72 + cb * 16 + idx15] = bf16_rne(tv - bf16_tof(hb2));
    }
  asm volatile("s_waitcnt lgkmcnt(0)" ::: "memory");
  __builtin_amdgcn_sched_barrier(0);
  short8 thi[2], tlo[2];
#pragma unroll
  for (int ks = 0; ks < 2; ++ks) {
    thi[ks] = *(const short8*)&tbh[wave][idx15 * 72 + ks * 32 + koff];
    tlo[ks] = *(const short8*)&tbl[wave][idx15 * 72 + ks * 32 + koff];
  }

  // MLP2 (+ wave1: self GEMM, A exact bf16 so no lo term); facc = partial
  f32x4 facc[4];
#pragma unroll
  for (int cb = 0; cb < 4; ++cb) {
    int c = cb * 16 + idx15;
    float bi = b2[((size_t)l * 2 + r) * 64 + c];
    if (wave == 1) bi += selfb[l * 64 + c];
    facc[cb] = (f32x4){bi, bi, bi, bi};
  }
#pragma unroll
  for (int cb = 0; cb < 4; ++cb) {
    int c = cb * 16 + idx15;
#pragma unroll
    for (int ks = 0; ks < 2; ++ks) {
      const short8 bh = *(const short8*)&whi[WOFF(m2, c, ks)];
      const short8 bl = *(const short8*)&wlo[WOFF(m2, c, ks)];
      facc[cb] = __builtin_amdgcn_mfma_f32_16x16x32_bf16(thi[ks], bh, facc[cb], 0, 0, 0);
      facc[cb] = __builtin_amdgcn_mfma_f32_16x16x32_bf16(thi[ks], bl, facc[cb], 0, 0, 0);
      facc[cb] = __builtin_amdgcn_mfma_f32_16x16x32_bf16(tlo[ks], bh, facc[cb], 0, 0, 0);
    }
  }
  if (wave == 1) {
    short8 ahi[2];
    ahi[0][0] = (short)(u0.x & 0xffff); ahi[0][1] = (short)(u0.x >> 16);
    ahi[0][2] = (short)(u0.y & 0xffff); ahi[0][3] = (short)(u0.y >> 16);
    ahi[0][4] = (short)(u0.z & 0xffff); ahi[0][5] = (short)(u0.z >> 16);
    ahi[0][6] = (short)(u0.w & 0xffff); ahi[0][7] = (short)(u0.w >> 16);
    ahi[1][0] = (short)(u1.x & 0xffff); ahi[1][1] = (short)(u1.x >> 16);
    ahi[1][2] = (short)(u1.y & 0xffff); ahi[1][3] = (short)(u1.y >> 16);
    ahi[1][4] = (short)(u1.z & 0xffff); ahi[1][5] = (short)(u1.z >> 16);
    ahi[1][6] = (short)(u1.w & 0xffff); ahi[1][7] = (short)(u1.w >> 16);
#pragma unroll
    for (int cb = 0; cb < 4; ++cb) {
      int c = cb * 16 + idx15;
#pragma unroll
      for (int ks = 0; ks < 2; ++ks) {
        const short8 bh = *(const short8*)&whi[WOFF(0, c, ks)];
        const short8 bl = *(const short8*)&wlo[WOFF(0, c, ks)];
        facc[cb] = __builtin_amdgcn_mfma_f32_16x16x32_bf16(ahi[ks], bh, facc[cb], 0, 0, 0);
        facc[cb] = __builtin_amdgcn_mfma_f32_16x16x32_bf16(ahi[ks], bl, facc[cb], 0, 0, 0);
      }
    }
  }
  __syncthreads();                      // all tb reads done -> safe to alias
  if (wave == 1) {
#pragma unroll
    for (int cb = 0; cb < 4; ++cb)
#pragma unroll
      for (int q = 0; q < 4; ++q)
        xfer[(kg * 4 + q) * 65 + cb * 16 + idx15] = facc[cb][q];
  }
  __syncthreads();
  if (wave == 0) {
#pragma unroll
    for (int cb = 0; cb < 4; ++cb)
#pragma unroll
      for (int q = 0; q < 4; ++q) {
        int row = kg * 4 + q, col = cb * 16 + idx15;
        float v = facc[cb][q] + xfer[row * 65 + col];
        hnb[((size_t)task * 16 + row) * 64 + col] = bf16_rne(v);
      }
  }
}

// ====== fused pool+head: 8 waves per graph, LDS combine, no atomics =========
__global__ __launch_bounds__(512) void k_poolhead(
    const unsigned short* __restrict__ hb, const int* __restrict__ batch,
    const float* __restrict__ l1W, const float* __restrict__ l1b,
    const float* __restrict__ l2W, const float* __restrict__ l2b,
    float* __restrict__ out)
{
  __shared__ float part[8][64];
  int g = blockIdx.x;
  int wave = threadIdx.x >> 6;
  int lane = threadIdx.x & 63;
  // [start, end) = rows of graph g (batch sorted ascending)
  int lo = 0, hi = Nn;
  while (lo < hi) { int mid = (lo + hi) >> 1; if (batch[mid] < g) lo = mid + 1; else hi = mid; }
  int start = lo;
  hi = Nn;
  while (lo < hi) { int mid = (lo + hi) >> 1; if (batch[mid] < g + 1) lo = mid + 1; else hi = mid; }
  int end = lo;

  float acc = 0.0f;
  for (int i = start + wave; i < end; i += 8)
    acc += bf16_tof(hb[(size_t)i * 64 + lane]);
  part[wave][lane] = acc;
  __syncthreads();
  if (wave == 0) {
    float s = 0.0f;
#pragma unroll
    for (int w = 0; w < 8; ++w) s += part[w][lane];
    float p = s / fmaxf((float)(end - start), 1.0f);
    float t = l1b[lane];
#pragma unroll
    for (int k = 0; k < Dd; ++k)
      t += __shfl(p, k, 64) * l1W[k * Dd + lane];
    t = fmaxf(t, 0.0f);
    float o = (lane < Cc) ? l2b[lane] : 0.0f;
#pragma unroll
    for (int k = 0; k < Dd; ++k) {
      float w = (lane < Cc) ? l2W[k * Cc + lane] : 0.0f;
      o += __shfl(t, k, 64) * w;
    }
    if (lane < Cc) out[(size_t)g * Cc + lane] = o;
  }
}

extern "C" void kernel_launch(void* const* d_in, const int* in_sizes, int n_in,
                              void* d_out, int out_size, void* d_ws, size_t ws_size,
                              hipStream_t stream)
{
  const float* x     = (const float*)d_in[0];
  const int*   ei    = (const int*)d_in[1];
  const int*   et    = (const int*)d_in[2];
  const int*   batch = (const int*)d_in[3];
  const float* selfW = (const float*)d_in[4];
  const float* selfb = (const float*)d_in[5];
  const float* eps   = (const float*)d_in[6];
  const float* W1    = (const float*)d_in[7];
  const float* b1    = (const float*)d_in[8];
  const float* W2    = (const float*)d_in[9];
  const float* b2    = (const float*)d_in[10];
  const float* l1W   = (const float*)d_in[11];
  const float* l1b   = (const float*)d_in[12];
  const float* l2W   = (const float*)d_in[13];
  const float* l2b   = (const float*)d_in[14];
  float* out = (float*)d_out;

  // ws layout:
  // hb0[N*D]u16 hb1[N*D]u16 wtHi/wtLo[15*4096]u16
  // counts[NR] offs[NR+1] cursor[NR] btot[NB] elist[EPAD] (16B-aligned)
  unsigned short* hb0 = (unsigned short*)d_ws;
  unsigned short* hb1 = hb0 + (size_t)Nn * Dd;
  unsigned short* wtHi = hb1 + (size_t)Nn * Dd;
  unsigned short* wtLo = wtHi + (size_t)Ll * 5 * 4096;
  int* counts = (int*)(wtLo + (size_t)Ll * 5 * 4096);
  int* offs   = counts + NR;
  int* cursor = offs + NR + 1;
  int* btot   = cursor + NR;
  int* elist  = (int*)((((uintptr_t)(btot + NB)) + 15) & ~(uintptr_t)15);

  const int* src = ei;
  const int* dst = ei + Ee;

  hipMemsetAsync(counts, 0, (size_t)NR * sizeof(int), stream);
  k_setup<<<CVT_B + PREP_B + HIST_B, 256, 0, stream>>>(
      x, hb0, selfW, W1, W2, wtHi, wtLo, dst, et, counts);

  // CSR build, padded segments (graph static across layers)
  k_scan1<<<NB, 1024, 0, stream>>>(counts, offs, btot);
  k_scan3<<<NB, 1024, 0, stream>>>(counts, btot, offs, cursor);
  k_fill<<<(Ee + 255) / 256, 256, 0, stream>>>(src, dst, et, cursor, elist);

  const unsigned short* hbc = hb0;
  unsigned short* hnb = hb1;
  for (int l = 0; l < Ll; ++l) {
    k_update<<<NT, 128, 0, stream>>>(hbc, offs, counts, elist, wtHi, wtLo,
                                     selfb, eps, b1, b2, hnb, l);
    hbc = hnb;
    hnb = (hnb == hb0) ? hb1 : hb0;
  }
  k_poolhead<<<Gg, 512, 0, stream>>>(hbc, batch, l1W, l1b, l2W, l2b, out);
}